// Round 7
// baseline (293.252 us; speedup 1.0000x reference)
//
#include <hip/hip_runtime.h>

// Transformer decoder block, MI355X gfx950. Round 7: tile-blocked (64x64)
// layouts for ALL transposed buffers (Tt, Xt, WqT, WkT, XoutT) so producer
// writes are fully coalesced; consumer GEMMs address tiles via per-lane
// staging pointers (TA_/TB_ compile-time flags, K-step 4096 elements).
//
// Dataflow (all GEMMs "TN": A is MxK K-fastest, Bt is NxK K-fastest, C = A·Bt^T):
//   WqT,WkT = transpose(Wq,Wk) bf16 (c,o)   [tiled]
//   G2  = WkT · WqT^T           (C,C)  bf16 (row-major)
//   Xt  = transpose(X_in) bf16  (B,N,C)     [tiled]
//   Tb,Tt = cast/transpose(T)   (B,C,L) row / (B,L,C) [tiled]
//   e   = Xt · G2^T             (B,N,C)   bf16
//   E   = exp(e·Tt^T / 32)      (B,N,L)   bf16  + row-sum partials
//   u   = (E · Tb^T) / rowsum   (B,N,C)   bf16
//   Z1  = Wv · u^T + X_in       (B,C,N)   bf16  + stats partials pp1
//   XoutT = LN(Z1) bf16 (N,C)   [tiled]
//   hT  = relu(XoutT · Wf1^T)   (B,N,C)   bf16
//   Z2  = transpose(hT·Wf2^T) + LN(Z1)    bf16  + partials pp2
//   out = LN(Z2) f32

using bf16   = __bf16;
using bf16x4 = __attribute__((ext_vector_type(4))) __bf16;
using bf16x8 = __attribute__((ext_vector_type(8))) __bf16;
using f32x4  = __attribute__((ext_vector_type(4))) float;

static constexpr int  Bb = 64;
static constexpr int  Cc = 1024;
static constexpr int  Nn = 128;
static constexpr int  Ll = 512;
static constexpr long long PLANE = (long long)Cc * Nn;  // 131072
static constexpr float INV_PLANE = 1.0f / 131072.0f;

__device__ __forceinline__ void gload_lds16(const void* g, void* l) {
    __builtin_amdgcn_global_load_lds(
        (__attribute__((address_space(1))) void*)g,
        (__attribute__((address_space(3))) void*)l,
        16, 0, 0);
}

// ---------------- all prep work in ONE launch ----------------
// blocks [0,3072): straight casts Wv/Wf1/Wf2 (1024 blocks each)
// blocks [3072,3584): Wq,Wk transposes (256 each) -> tiled
// blocks [3584,5632): Xt (64 batches x 2 x 16)    -> tiled
// blocks [5632,13824): T dual (64 x 8 x 16)       -> Tb row-major + Tt tiled
__global__ void __launch_bounds__(256)
prep_all(const float* __restrict__ Wv, const float* __restrict__ Wf1,
         const float* __restrict__ Wf2, const float* __restrict__ Wq,
         const float* __restrict__ Wk, const float* __restrict__ X,
         const float* __restrict__ T,
         bf16* __restrict__ WvB, bf16* __restrict__ Wf1B, bf16* __restrict__ Wf2B,
         bf16* __restrict__ WqT, bf16* __restrict__ WkT,
         bf16* __restrict__ Xt, bf16* __restrict__ Tt, bf16* __restrict__ Tb) {
    __shared__ float tile[64][65];
    const int bx = blockIdx.x;
    const int t  = threadIdx.x;
    if (bx < 3072) {
        const float* in = bx < 1024 ? Wv : (bx < 2048 ? Wf1 : Wf2);
        bf16* out       = bx < 1024 ? WvB : (bx < 2048 ? Wf1B : Wf2B);
        int i = (bx & 1023) * 256 + t;
        float4 v = reinterpret_cast<const float4*>(in)[i];
        bf16x4 o = { (bf16)v.x, (bf16)v.y, (bf16)v.z, (bf16)v.w };
        reinterpret_cast<bf16x4*>(out)[i] = o;
        return;
    }
    const float* in; bf16* outT; bf16* outS = nullptr;
    int R, S, bxx, byy, bz = 0;
    if (bx < 3584) {
        int j = bx - 3072;
        in = (j >= 256) ? Wk : Wq; outT = (j >= 256) ? WkT : WqT;
        R = Cc; S = Cc; j &= 255; bxx = j & 15; byy = j >> 4;
    } else if (bx < 5632) {
        int j = bx - 3584; bz = j >> 5; j &= 31;
        bxx = j & 1; byy = j >> 1; in = X; outT = Xt; R = Cc; S = Nn;
    } else {
        int j = bx - 5632; bz = j >> 7; j &= 127;
        bxx = j & 7; byy = j >> 3; in = T; outT = Tt; outS = Tb; R = Cc; S = Ll;
    }
    long long plane = (long long)R * S;
    in   += (long long)bz * plane;
    outT += (long long)bz * plane;
    if (outS) outS += (long long)bz * plane;
    int s0 = bxx * 64, r0 = byy * 64;
    int rl = t >> 4;            // 0..15
    int sc = (t & 15) * 4;      // 0..60
    #pragma unroll
    for (int p = 0; p < 4; ++p) {
        int r = p * 16 + rl;
        float4 v = *(const float4*)(in + (long long)(r0 + r) * S + s0 + sc);
        *(float4*)&tile[r][sc] = v;
        if (outS) {
            bf16x4 o = { (bf16)v.x, (bf16)v.y, (bf16)v.z, (bf16)v.w };
            *(bf16x4*)(outS + (long long)(r0 + r) * S + s0 + sc) = o;
        }
    }
    __syncthreads();
    // tiled transposed write: tile (s0/64, r0/64) is 4096 contiguous elements
    long long tb = ((long long)(s0 >> 6) * (R >> 6) + (r0 >> 6)) * 4096;
    int sb = t >> 3;            // 0..31
    int rg = (t & 7) * 8;       // 0..56
    #pragma unroll
    for (int p = 0; p < 2; ++p) {
        int s = sb + p * 32;
        bf16x8 o;
        #pragma unroll
        for (int j = 0; j < 8; ++j) o[j] = (bf16)tile[rg + j][s];
        *(bf16x8*)(outT + tb + s * 64 + rg) = o;
    }
}

// ---------------- TN GEMM core: 128x128 tile, BK=64, double-buffered 2-phase ----------------
// TA_/TB_: 0 = row-major (stride K), 1 = 64x64-tiled (tile stride 4096).
// Staging: global_load_lds width-16, linear LDS dest, source pre-swizzled by
// byte ^= ((row&7)<<4); fragment ds_read_b128 applies the same XOR (rule #21).
#define GEMM_PROLOGUE_AND_LOOP(A_, Bt_, K_, TA_, TB_)                              \
    __shared__ bf16 As[2][128 * 64];                                               \
    __shared__ bf16 Bs[2][128 * 64];                                               \
    const int n0   = blockIdx.x * 128;                                             \
    const int m0   = blockIdx.y * 128;                                             \
    const int t    = threadIdx.x;                                                  \
    const int lane = t & 63;                                                       \
    const int w    = t >> 6;                                                       \
    const int wr   = (w >> 1) * 64;                                                \
    const int wc   = (w & 1) * 64;                                                 \
    const int lr   = lane & 15;                                                    \
    const int hi4  = (lane >> 4) * 16;                                             \
    const int sw   = (lr & 7) << 4;                                                \
    const int stepA_ = (TA_) ? 4096 : 64;                                          \
    const int stepB_ = (TB_) ? 4096 : 64;                                          \
    const bf16* gA[4]; const bf16* gB[4]; int lo[4];                               \
    _Pragma("unroll")                                                              \
    for (int p = 0; p < 4; ++p) {                                                  \
        int o = w * 1024 + lane * 16 + p * 4096;                                   \
        int row = o >> 7;                                                          \
        int scol = ((o & 127) ^ ((row & 7) << 4)) >> 1;                            \
        lo[p] = o;                                                                 \
        int ra = m0 + row, rb = n0 + row;                                          \
        gA[p] = (TA_) ? A_ + ((long long)(ra >> 6) * (K_ >> 6)) * 4096             \
                           + (ra & 63) * 64 + scol                                 \
                      : A_ + (long long)ra * K_ + scol;                            \
        gB[p] = (TB_) ? Bt_ + ((long long)(rb >> 6) * (K_ >> 6)) * 4096            \
                            + (rb & 63) * 64 + scol                                \
                      : Bt_ + (long long)rb * K_ + scol;                           \
    }                                                                              \
    f32x4 acc[4][4] = {};                                                          \
    const int NT_ = K_ / 64;                                                       \
    _Pragma("unroll")                                                              \
    for (int p = 0; p < 4; ++p) gload_lds16(gA[p], (char*)As[0] + lo[p]);          \
    _Pragma("unroll")                                                              \
    for (int p = 0; p < 4; ++p) gload_lds16(gB[p], (char*)Bs[0] + lo[p]);          \
    __syncthreads();                                                               \
    int cur_ = 0;                                                                  \
    for (int kt = 0; kt < NT_; ++kt) {                                             \
        if (kt + 1 < NT_) {                                                        \
            _Pragma("unroll")                                                      \
            for (int p = 0; p < 4; ++p)                                            \
                gload_lds16(gA[p] + (long long)(kt + 1) * stepA_,                  \
                            (char*)As[cur_ ^ 1] + lo[p]);                          \
            _Pragma("unroll")                                                      \
            for (int p = 0; p < 4; ++p)                                            \
                gload_lds16(gB[p] + (long long)(kt + 1) * stepB_,                  \
                            (char*)Bs[cur_ ^ 1] + lo[p]);                          \
        }                                                                          \
        const bf16* As_ = As[cur_]; const bf16* Bs_ = Bs[cur_];                    \
        _Pragma("unroll")                                                          \
        for (int kk = 0; kk < 2; ++kk) {                                           \
            bf16x8 af[4], bfr[4];                                                  \
            _Pragma("unroll")                                                      \
            for (int i = 0; i < 4; ++i) {                                          \
                int ra = wr + i * 16 + lr;                                         \
                int rb = wc + i * 16 + lr;                                         \
                af[i]  = *(const bf16x8*)((const char*)As_ +                       \
                          ((((ra << 7) + (kk << 6) + hi4)) ^ sw));                 \
                bfr[i] = *(const bf16x8*)((const char*)Bs_ +                       \
                          ((((rb << 7) + (kk << 6) + hi4)) ^ sw));                 \
            }                                                                      \
            _Pragma("unroll")                                                      \
            for (int mi = 0; mi < 4; ++mi)                                         \
                _Pragma("unroll")                                                  \
                for (int ni = 0; ni < 4; ++ni)                                     \
                    acc[mi][ni] = __builtin_amdgcn_mfma_f32_16x16x32_bf16(         \
                        af[mi], bfr[ni], acc[mi][ni], 0, 0, 0);                    \
        }                                                                          \
        __syncthreads();                                                           \
        cur_ ^= 1;                                                                 \
    }

// plain TN GEMM: C[M,N] = scale * A·Bt^T  (+optional relu)
template <typename OutT, bool RELU, int TA, int TB>
__global__ void __launch_bounds__(256, 2)
gemm_tn(const bf16* __restrict__ A, const bf16* __restrict__ Bt, OutT* __restrict__ C,
        int M, int N, int K, long long sA, long long sBt, long long sC, float scale) {
    A  += (long long)blockIdx.z * sA;
    Bt += (long long)blockIdx.z * sBt;
    C  += (long long)blockIdx.z * sC;
    GEMM_PROLOGUE_AND_LOOP(A, Bt, K, TA, TB)
    const int rbase = m0 + wr + (lane >> 4) * 4;
    const int cbase = n0 + wc + lr;
    #pragma unroll
    for (int mi = 0; mi < 4; ++mi)
        #pragma unroll
        for (int ni = 0; ni < 4; ++ni)
            #pragma unroll
            for (int r = 0; r < 4; ++r) {
                float v = acc[mi][ni][r] * scale;
                if (RELU) v = fmaxf(v, 0.0f);
                C[(long long)(rbase + mi * 16 + r) * N + (cbase + ni * 16)] = (OutT)v;
            }
}

// sim GEMM + fused exp + per-tile row sums (A=e row-major, B=Tt tiled):
// E[n,l] = exp(acc/32) bf16 ; rspart[(b*4+bx)*128 + n] = sum_l(tile) E
__global__ void __launch_bounds__(256, 2)
gemm_sim_exp(const bf16* __restrict__ A /*e*/, const bf16* __restrict__ Bt /*Tt*/,
             bf16* __restrict__ E, float* __restrict__ rspart, int K,
             long long sA, long long sBt) {
    A  += (long long)blockIdx.z * sA;
    Bt += (long long)blockIdx.z * sBt;
    E  += (long long)blockIdx.z * ((long long)Nn * Ll);
    GEMM_PROLOGUE_AND_LOOP(A, Bt, K, 0, 1)
    const int rbase = m0 + wr + (lane >> 4) * 4;   // m0 == 0 (grid.y==1)
    const int cbase = n0 + wc + lr;                // l index
    __shared__ float rs[2][128];
    float psum[4][4];
    #pragma unroll
    for (int mi = 0; mi < 4; ++mi)
        #pragma unroll
        for (int r = 0; r < 4; ++r) psum[mi][r] = 0.f;
    #pragma unroll
    for (int mi = 0; mi < 4; ++mi)
        #pragma unroll
        for (int ni = 0; ni < 4; ++ni)
            #pragma unroll
            for (int r = 0; r < 4; ++r) {
                float ev = __expf(acc[mi][ni][r] * 0.03125f);
                E[(long long)(rbase + mi * 16 + r) * Ll + (cbase + ni * 16)] = (bf16)ev;
                psum[mi][r] += ev;
            }
    #pragma unroll
    for (int mi = 0; mi < 4; ++mi)
        #pragma unroll
        for (int r = 0; r < 4; ++r) {
            float v = psum[mi][r];
            v += __shfl_xor(v, 1); v += __shfl_xor(v, 2);
            v += __shfl_xor(v, 4); v += __shfl_xor(v, 8);
            psum[mi][r] = v;
        }
    if (lr == 0) {
        #pragma unroll
        for (int mi = 0; mi < 4; ++mi)
            #pragma unroll
            for (int r = 0; r < 4; ++r)
                rs[wc ? 1 : 0][wr + (lane >> 4) * 4 + mi * 16 + r] = psum[mi][r];
    }
    __syncthreads();
    if (t < 128)
        rspart[((long long)blockIdx.z * 4 + blockIdx.x) * 128 + t] = rs[0][t] + rs[1][t];
}

// u GEMM with row-wise softmax normalization folded into the epilogue:
// u[n,c] = (E · Tb^T)[n,c] / rowsum[n]
__global__ void __launch_bounds__(256, 2)
gemm_u_scaled(const bf16* __restrict__ A /*E*/, const bf16* __restrict__ Bt /*Tb*/,
              bf16* __restrict__ C, const float* __restrict__ rspart, int K,
              long long sA, long long sBt, long long sC) {
    A  += (long long)blockIdx.z * sA;
    Bt += (long long)blockIdx.z * sBt;
    C  += (long long)blockIdx.z * sC;
    const float* rp = rspart + (long long)blockIdx.z * 512;
    GEMM_PROLOGUE_AND_LOOP(A, Bt, K, 0, 0)
    const int rbase = m0 + wr + (lane >> 4) * 4;   // n (m0==0)
    const int cbase = n0 + wc + lr;                // c
    #pragma unroll
    for (int mi = 0; mi < 4; ++mi)
        #pragma unroll
        for (int r = 0; r < 4; ++r) {
            int row = rbase + mi * 16 + r;
            float inv = 1.f / (rp[row] + rp[128 + row] + rp[256 + row] + rp[384 + row]);
            #pragma unroll
            for (int ni = 0; ni < 4; ++ni)
                C[(long long)row * Cc + (cbase + ni * 16)] = (bf16)(acc[mi][ni][r] * inv);
        }
}

// ctx GEMM + LN1 residual/stats epilogue (Z1 stored bf16):
__global__ void __launch_bounds__(256, 2)
gemm_ctx_ln1(const bf16* __restrict__ A /*Wv*/, const bf16* __restrict__ Bt /*u*/,
             const float* __restrict__ X, bf16* __restrict__ Z1, float* __restrict__ partials,
             int K, long long sBt) {
    const int N = Nn;
    Bt += (long long)blockIdx.z * sBt;
    X  += (long long)blockIdx.z * PLANE;
    Z1 += (long long)blockIdx.z * PLANE;
    GEMM_PROLOGUE_AND_LOOP(A, Bt, K, 0, 0)
    const int rbase = m0 + wr + (lane >> 4) * 4;
    const int cbase = n0 + wc + lr;   // n0 == 0 (grid.x==1)
    float s = 0.f, ss = 0.f;
    #pragma unroll
    for (int mi = 0; mi < 4; ++mi)
        #pragma unroll
        for (int ni = 0; ni < 4; ++ni)
            #pragma unroll
            for (int r = 0; r < 4; ++r) {
                long long idx = (long long)(rbase + mi * 16 + r) * N + (cbase + ni * 16);
                float zv = acc[mi][ni][r] + X[idx];
                Z1[idx] = (bf16)zv;
                s += zv; ss += zv * zv;
            }
    #pragma unroll
    for (int off = 32; off; off >>= 1) { s += __shfl_xor(s, off); ss += __shfl_xor(ss, off); }
    __shared__ float red[8];
    if (lane == 0) { red[w] = s; red[4 + w] = ss; }
    __syncthreads();
    if (t == 0) {
        float S = red[0] + red[1] + red[2] + red[3];
        float SS = red[4] + red[5] + red[6] + red[7];
        float* p = partials + ((long long)blockIdx.z * 8 + blockIdx.y) * 2;
        p[0] = S; p[1] = SS;
    }
}

// FFN GEMM + LN2 epilogue: Xout recomputed from bf16 Z1 + LN1 stats; Z2 stored bf16.
__global__ void __launch_bounds__(256, 2)
gemm_ffn_ln2(const bf16* __restrict__ A /*hT*/, const bf16* __restrict__ Bt /*Wf2*/,
             const bf16* __restrict__ Z1, const float* __restrict__ pp1,
             const float* __restrict__ gamma, const float* __restrict__ beta,
             bf16* __restrict__ Z2, float* __restrict__ partials,
             int K, long long sA) {
    A  += (long long)blockIdx.z * sA;
    Z1 += (long long)blockIdx.z * PLANE;
    Z2 += (long long)blockIdx.z * PLANE;
    float S1 = 0.f, SS1 = 0.f;
    #pragma unroll
    for (int j = 0; j < 8; ++j) {
        S1  += pp1[((long long)blockIdx.z * 8 + j) * 2];
        SS1 += pp1[((long long)blockIdx.z * 8 + j) * 2 + 1];
    }
    const float mean1 = S1 * INV_PLANE;
    const float rstd1 = rsqrtf(SS1 * INV_PLANE - mean1 * mean1 + 1e-5f);
    GEMM_PROLOGUE_AND_LOOP(A, Bt, K, 0, 0)
    const int rbase = m0 + wr + (lane >> 4) * 4;   // n index (m0==0)
    const int cbase = n0 + wc + lr;                // c index
    float s = 0.f, ss = 0.f;
    #pragma unroll
    for (int mi = 0; mi < 4; ++mi)
        #pragma unroll
        for (int ni = 0; ni < 4; ++ni) {
            long long a = (long long)(cbase + ni * 16) * Nn + rbase + mi * 16;
            bf16x4 z1v = *(const bf16x4*)(Z1 + a);
            float4 g  = *(const float4*)(gamma + a);
            float4 be = *(const float4*)(beta + a);
            float x0 = ((float)z1v[0] - mean1) * rstd1 * g.x + be.x;
            float x1 = ((float)z1v[1] - mean1) * rstd1 * g.y + be.y;
            float x2 = ((float)z1v[2] - mean1) * rstd1 * g.z + be.z;
            float x3 = ((float)z1v[3] - mean1) * rstd1 * g.w + be.w;
            float z0 = acc[mi][ni][0] + x0, z1 = acc[mi][ni][1] + x1;
            float z2 = acc[mi][ni][2] + x2, z3 = acc[mi][ni][3] + x3;
            bf16x4 zo = { (bf16)z0, (bf16)z1, (bf16)z2, (bf16)z3 };
            *(bf16x4*)(Z2 + a) = zo;
            s  += z0 + z1 + z2 + z3;
            ss += z0 * z0 + z1 * z1 + z2 * z2 + z3 * z3;
        }
    #pragma unroll
    for (int off = 32; off; off >>= 1) { s += __shfl_xor(s, off); ss += __shfl_xor(ss, off); }
    __shared__ float red[8];
    if (lane == 0) { red[w] = s; red[4 + w] = ss; }
    __syncthreads();
    if (t == 0) {
        float S = red[0] + red[1] + red[2] + red[3];
        float SS = red[4] + red[5] + red[6] + red[7];
        float* p = partials + ((long long)blockIdx.z * 8 + blockIdx.x) * 2;
        p[0] = S; p[1] = SS;
    }
}

// ---------------- LN1 normalize (bf16 Z1) + tiled transposed bf16 output ----------------
__global__ void ln1_norm_transpose(const bf16* __restrict__ Z1, const float* __restrict__ partials,
                                   const float* __restrict__ gamma, const float* __restrict__ beta,
                                   bf16* __restrict__ XoutT) {
    int b = blockIdx.z;
    float S = 0.f, SS = 0.f;
    #pragma unroll
    for (int j = 0; j < 8; ++j) {
        S  += partials[((long long)b * 8 + j) * 2];
        SS += partials[((long long)b * 8 + j) * 2 + 1];
    }
    float mean = S * INV_PLANE;
    float var  = SS * INV_PLANE - mean * mean;
    float rstd = rsqrtf(var + 1e-5f);
    __shared__ float tile[64][65];
    long long base = (long long)b * PLANE;
    int n0 = blockIdx.x * 64, c0 = blockIdx.y * 64;
    int t = threadIdx.x;
    int rl = t >> 4;            // local c, 0..15
    int sc = (t & 15) * 4;      // local n
    #pragma unroll
    for (int p = 0; p < 4; ++p) {
        int r = p * 16 + rl;
        long long idx = (long long)(c0 + r) * Nn + n0 + sc;
        bf16x4 z  = *(const bf16x4*)(Z1 + base + idx);
        float4 g  = *(const float4*)(gamma + idx);
        float4 be = *(const float4*)(beta + idx);
        float4 o = {((float)z[0] - mean) * rstd * g.x + be.x,
                    ((float)z[1] - mean) * rstd * g.y + be.y,
                    ((float)z[2] - mean) * rstd * g.z + be.z,
                    ((float)z[3] - mean) * rstd * g.w + be.w};
        *(float4*)&tile[r][sc] = o;
    }
    __syncthreads();
    // tiled write: XoutT tile (n0/64, c0/64), 4096 contiguous elements
    long long tb = ((long long)(n0 >> 6) * (Cc >> 6) + (c0 >> 6)) * 4096;
    int sb = t >> 3;            // local n, 0..31
    int rg = (t & 7) * 8;       // local c group
    #pragma unroll
    for (int p = 0; p < 2; ++p) {
        int n = sb + p * 32;
        bf16x8 o;
        #pragma unroll
        for (int j = 0; j < 8; ++j) o[j] = (bf16)tile[rg + j][n];
        *(bf16x8*)(XoutT + base + tb + n * 64 + rg) = o;
    }
}

// ---------------- final LN: out = (Z2-mean)*rstd*gamma+beta, bf16 Z2 -> f32 out ----------------
__global__ void ln2_final(const bf16* __restrict__ Z2, const float* __restrict__ partials,
                          const float* __restrict__ gamma, const float* __restrict__ beta,
                          float* __restrict__ out) {
    int b = blockIdx.y;
    float S = 0.f, SS = 0.f;
    #pragma unroll
    for (int j = 0; j < 8; ++j) {
        S  += partials[((long long)b * 8 + j) * 2];
        SS += partials[((long long)b * 8 + j) * 2 + 1];
    }
    float mean = S * INV_PLANE;
    float var  = SS * INV_PLANE - mean * mean;
    float rstd = rsqrtf(var + 1e-5f);
    long long base = (long long)b * PLANE;
    int i = (blockIdx.x * 256 + threadIdx.x) * 8;
    bf16x8 z = *(const bf16x8*)(Z2 + base + i);
    #pragma unroll
    for (int h = 0; h < 2; ++h) {
        float4 g  = *(const float4*)(gamma + i + h * 4);
        float4 be = *(const float4*)(beta + i + h * 4);
        float4 o = {((float)z[h * 4 + 0] - mean) * rstd * g.x + be.x,
                    ((float)z[h * 4 + 1] - mean) * rstd * g.y + be.y,
                    ((float)z[h * 4 + 2] - mean) * rstd * g.z + be.z,
                    ((float)z[h * 4 + 3] - mean) * rstd * g.w + be.w};
        *(float4*)(out + base + i + h * 4) = o;
    }
}

extern "C" void kernel_launch(void* const* d_in, const int* in_sizes, int n_in,
                              void* d_out, int out_size, void* d_ws, size_t ws_size,
                              hipStream_t stream) {
    const float* X   = (const float*)d_in[0];
    const float* T   = (const float*)d_in[1];
    const float* Wq  = (const float*)d_in[2];
    const float* Wk  = (const float*)d_in[3];
    const float* Wv  = (const float*)d_in[4];
    const float* Wf1 = (const float*)d_in[5];
    const float* Wf2 = (const float*)d_in[6];
    const float* gamma = (const float*)d_in[7];
    const float* beta  = (const float*)d_in[8];
    float* out = (float*)d_out;
    char* ws = (char*)d_ws;
    const size_t MB = 1ull << 20;

    // workspace (aliased by liveness):
    bf16* WvB  = (bf16*)(ws + 0 * MB);     // 2 MB
    bf16* Wf1B = (bf16*)(ws + 2 * MB);     // 2 MB
    bf16* Wf2B = (bf16*)(ws + 4 * MB);     // 2 MB
    bf16* WqT  = (bf16*)(ws + 6 * MB);     // 2 MB (tiled)
    bf16* WkT  = (bf16*)(ws + 8 * MB);     // 2 MB (tiled)
    bf16* G2   = (bf16*)(ws + 10 * MB);    // 2 MB
    bf16* Xt   = (bf16*)(ws + 12 * MB);    // 16 MB (tiled)
    bf16* Tt   = (bf16*)(ws + 28 * MB);    // 64 MB (tiled); dead after sim_exp
    bf16* Z1   = (bf16*)(ws + 28 * MB);    //   alias: 16 MB
    bf16* Tb   = (bf16*)(ws + 92 * MB);    // 64 MB; dead after u gemm
    bf16* XoutT= (bf16*)(ws + 92 * MB);    //   alias: 16 MB (tiled)
    bf16* hT   = (bf16*)(ws + 108 * MB);   //   alias: 16 MB
    bf16* e    = (bf16*)(ws + 156 * MB);   // 16 MB; dead after sim_exp
    bf16* Z2   = (bf16*)(ws + 156 * MB);   //   alias: 16 MB
    bf16* E    = (bf16*)(ws + 188 * MB);   // 8 MB
    bf16* u    = (bf16*)(ws + 196 * MB);   // 16 MB
    float* pp1 = (float*)(ws + 212 * MB);  // 1 KB
    float* pp2 = (float*)(ws + 212 * MB + 65536);
    float* rsp = (float*)(ws + 213 * MB);  // 128 KB

    dim3 blk256(256);

    // 1. all prep (weight casts, weight transposes, Xt, T dual) in one launch
    prep_all<<<dim3(13824), blk256, 0, stream>>>(
        Wv, Wf1, Wf2, Wq, Wk, X, T, WvB, Wf1B, Wf2B, WqT, WkT, Xt, Tt, Tb);

    // 2. G2 = WkT·WqT^T  [1024,1024,1024] (A,B tiled)
    gemm_tn<bf16, false, 1, 1><<<dim3(8, 8, 1), blk256, 0, stream>>>(
        WkT, WqT, G2, Cc, Cc, Cc, 0, 0, 0, 1.f);
    // 3. e = Xt·G2^T  [128,1024,1024]  (A tiled)
    gemm_tn<bf16, false, 1, 0><<<dim3(8, 1, Bb), blk256, 0, stream>>>(
        Xt, G2, e, Nn, Cc, Cc, (long long)Nn * Cc, 0, (long long)Nn * Cc, 1.f);
    // 4. E = exp(e·Tt^T/32) + row-sum partials  [128,512,1024] (B tiled)
    gemm_sim_exp<<<dim3(4, 1, Bb), blk256, 0, stream>>>(
        e, Tt, E, rsp, Cc, (long long)Nn * Cc, (long long)Ll * Cc);
    // 5. u = (E·Tb^T)/rowsum  [128,1024,512]
    gemm_u_scaled<<<dim3(8, 1, Bb), blk256, 0, stream>>>(
        E, Tb, u, rsp, Ll, (long long)Nn * Ll, (long long)Cc * Ll, (long long)Nn * Cc);
    // 6. Z1 = Wv·u^T + X  [1024,128,1024] + stats partials (bf16 Z1)
    gemm_ctx_ln1<<<dim3(1, 8, Bb), blk256, 0, stream>>>(
        WvB, u, X, Z1, pp1, Cc, (long long)Nn * Cc);
    // 7. LN1 -> XoutT (N,C) bf16 tiled
    ln1_norm_transpose<<<dim3(Nn / 64, Cc / 64, Bb), blk256, 0, stream>>>(
        Z1, pp1, gamma, beta, XoutT);
    // 8. hT = relu(XoutT·Wf1^T)  [128,1024,1024] (A tiled)
    gemm_tn<bf16, true, 1, 0><<<dim3(8, 1, Bb), blk256, 0, stream>>>(
        XoutT, Wf1B, hT, Nn, Cc, Cc, (long long)Nn * Cc, 0, (long long)Nn * Cc, 1.f);
    // 9. Z2 = transpose(hT·Wf2^T) + LN1(Z1)  [128,1024,1024] + partials (bf16 Z2)
    gemm_ffn_ln2<<<dim3(8, 1, Bb), blk256, 0, stream>>>(
        hT, Wf2B, Z1, pp1, gamma, beta, Z2, pp2, Cc, (long long)Nn * Cc);
    // 10. LN2 -> out (f32)
    ln2_final<<<dim3(64, Bb), blk256, 0, stream>>>(Z2, pp2, gamma, beta, out);
}

// Round 8
// 285.623 us; speedup vs baseline: 1.0267x; 1.0267x over previous
//
#include <hip/hip_runtime.h>

// Transformer decoder block, MI355X gfx950. Round 8:
//  - Tt/Tb ELIMINATED: sim-GEMM does in-LDS transpose staging of f32 T;
//    u-GEMM reg-stages f32 T in natural orientation. prep shrinks to weights+Xt.
//  - G2 split-K=4 (grid 64->256) + f32-partial reduce.
//
// Dataflow:
//   WqT,WkT = transpose(Wq,Wk) bf16 [tiled] ; G2 = WkT·WqT^T (split-K, f32->bf16)
//   Xt  = transpose(X_in) bf16 (B,N,C) [tiled]
//   e   = Xt · G2^T             (B,N,C)  bf16
//   E   = exp((e·T^T-staged)/32)(B,N,L)  bf16 + row-sum partials
//   u   = (E · T-staged) / rowsum (B,N,C) bf16
//   Z1  = Wv · u^T + X_in       (B,C,N)  bf16 + stats pp1
//   XoutT = LN(Z1) bf16 (N,C) [tiled]
//   hT  = relu(XoutT · Wf1^T)   (B,N,C)  bf16
//   Z2  = transpose(hT·Wf2^T) + LN(Z1)   bf16 + pp2
//   out = LN(Z2) f32

using bf16   = __bf16;
using bf16x4 = __attribute__((ext_vector_type(4))) __bf16;
using bf16x8 = __attribute__((ext_vector_type(8))) __bf16;
using f32x4  = __attribute__((ext_vector_type(4))) float;

static constexpr int  Bb = 64;
static constexpr int  Cc = 1024;
static constexpr int  Nn = 128;
static constexpr int  Ll = 512;
static constexpr long long PLANE = (long long)Cc * Nn;
static constexpr float INV_PLANE = 1.0f / 131072.0f;

__device__ __forceinline__ void gload_lds16(const void* g, void* l) {
    __builtin_amdgcn_global_load_lds(
        (__attribute__((address_space(1))) void*)g,
        (__attribute__((address_space(3))) void*)l,
        16, 0, 0);
}

// ---------------- prep: weight casts + Wq/Wk transposes + Xt (tiled) ----------------
// blocks [0,3072): casts Wv/Wf1/Wf2; [3072,3584): WqT/WkT; [3584,5632): Xt
__global__ void __launch_bounds__(256)
prep_all(const float* __restrict__ Wv, const float* __restrict__ Wf1,
         const float* __restrict__ Wf2, const float* __restrict__ Wq,
         const float* __restrict__ Wk, const float* __restrict__ X,
         bf16* __restrict__ WvB, bf16* __restrict__ Wf1B, bf16* __restrict__ Wf2B,
         bf16* __restrict__ WqT, bf16* __restrict__ WkT, bf16* __restrict__ Xt) {
    __shared__ float tile[64][65];
    const int bx = blockIdx.x;
    const int t  = threadIdx.x;
    if (bx < 3072) {
        const float* in = bx < 1024 ? Wv : (bx < 2048 ? Wf1 : Wf2);
        bf16* out       = bx < 1024 ? WvB : (bx < 2048 ? Wf1B : Wf2B);
        int i = (bx & 1023) * 256 + t;
        float4 v = reinterpret_cast<const float4*>(in)[i];
        bf16x4 o = { (bf16)v.x, (bf16)v.y, (bf16)v.z, (bf16)v.w };
        reinterpret_cast<bf16x4*>(out)[i] = o;
        return;
    }
    const float* in; bf16* outT;
    int R, S, bxx, byy, bz = 0;
    if (bx < 3584) {
        int j = bx - 3072;
        in = (j >= 256) ? Wk : Wq; outT = (j >= 256) ? WkT : WqT;
        R = Cc; S = Cc; j &= 255; bxx = j & 15; byy = j >> 4;
    } else {
        int j = bx - 3584; bz = j >> 5; j &= 31;
        bxx = j & 1; byy = j >> 1; in = X; outT = Xt; R = Cc; S = Nn;
    }
    long long plane = (long long)R * S;
    in   += (long long)bz * plane;
    outT += (long long)bz * plane;
    int s0 = bxx * 64, r0 = byy * 64;
    int rl = t >> 4, sc = (t & 15) * 4;
    #pragma unroll
    for (int p = 0; p < 4; ++p) {
        int r = p * 16 + rl;
        float4 v = *(const float4*)(in + (long long)(r0 + r) * S + s0 + sc);
        *(float4*)&tile[r][sc] = v;
    }
    __syncthreads();
    long long tb = ((long long)(s0 >> 6) * (R >> 6) + (r0 >> 6)) * 4096;
    int sb = t >> 3, rg = (t & 7) * 8;
    #pragma unroll
    for (int p = 0; p < 2; ++p) {
        int s = sb + p * 32;
        bf16x8 o;
        #pragma unroll
        for (int j = 0; j < 8; ++j) o[j] = (bf16)tile[rg + j][s];
        *(bf16x8*)(outT + tb + s * 64 + rg) = o;
    }
}

// ---------------- generic TN GEMM core (gload-staged both sides) ----------------
// KLOOP_: K extent of this kernel's loop; LD_: full row stride / tile-grid K extent.
#define GEMM_PROLOGUE_AND_LOOP(A_, Bt_, KLOOP_, LD_, TA_, TB_)                     \
    __shared__ bf16 As[2][128 * 64];                                               \
    __shared__ bf16 Bs[2][128 * 64];                                               \
    const int n0   = blockIdx.x * 128;                                             \
    const int m0   = blockIdx.y * 128;                                             \
    const int t    = threadIdx.x;                                                  \
    const int lane = t & 63;                                                       \
    const int w    = t >> 6;                                                       \
    const int wr   = (w >> 1) * 64;                                                \
    const int wc   = (w & 1) * 64;                                                 \
    const int lr   = lane & 15;                                                    \
    const int hi4  = (lane >> 4) * 16;                                             \
    const int sw   = (lr & 7) << 4;                                                \
    const int stepA_ = (TA_) ? 4096 : 64;                                          \
    const int stepB_ = (TB_) ? 4096 : 64;                                          \
    const bf16* gA[4]; const bf16* gB[4]; int lo[4];                               \
    _Pragma("unroll")                                                              \
    for (int p = 0; p < 4; ++p) {                                                  \
        int o = w * 1024 + lane * 16 + p * 4096;                                   \
        int row = o >> 7;                                                          \
        int scol = ((o & 127) ^ ((row & 7) << 4)) >> 1;                            \
        lo[p] = o;                                                                 \
        int ra = m0 + row, rb = n0 + row;                                          \
        gA[p] = (TA_) ? A_ + ((long long)(ra >> 6) * (LD_ >> 6)) * 4096            \
                           + (ra & 63) * 64 + scol                                 \
                      : A_ + (long long)ra * LD_ + scol;                           \
        gB[p] = (TB_) ? Bt_ + ((long long)(rb >> 6) * (LD_ >> 6)) * 4096           \
                            + (rb & 63) * 64 + scol                                \
                      : Bt_ + (long long)rb * LD_ + scol;                          \
    }                                                                              \
    f32x4 acc[4][4] = {};                                                          \
    const int NT_ = KLOOP_ / 64;                                                   \
    _Pragma("unroll")                                                              \
    for (int p = 0; p < 4; ++p) gload_lds16(gA[p], (char*)As[0] + lo[p]);          \
    _Pragma("unroll")                                                              \
    for (int p = 0; p < 4; ++p) gload_lds16(gB[p], (char*)Bs[0] + lo[p]);          \
    __syncthreads();                                                               \
    int cur_ = 0;                                                                  \
    for (int kt = 0; kt < NT_; ++kt) {                                             \
        if (kt + 1 < NT_) {                                                        \
            _Pragma("unroll")                                                      \
            for (int p = 0; p < 4; ++p)                                            \
                gload_lds16(gA[p] + (long long)(kt + 1) * stepA_,                  \
                            (char*)As[cur_ ^ 1] + lo[p]);                          \
            _Pragma("unroll")                                                      \
            for (int p = 0; p < 4; ++p)                                            \
                gload_lds16(gB[p] + (long long)(kt + 1) * stepB_,                  \
                            (char*)Bs[cur_ ^ 1] + lo[p]);                          \
        }                                                                          \
        const bf16* As_ = As[cur_]; const bf16* Bs_ = Bs[cur_];                    \
        _Pragma("unroll")                                                          \
        for (int kk = 0; kk < 2; ++kk) {                                           \
            bf16x8 af[4], bfr[4];                                                  \
            _Pragma("unroll")                                                      \
            for (int i = 0; i < 4; ++i) {                                          \
                int ra = wr + i * 16 + lr;                                         \
                int rb = wc + i * 16 + lr;                                         \
                af[i]  = *(const bf16x8*)((const char*)As_ +                       \
                          ((((ra << 7) + (kk << 6) + hi4)) ^ sw));                 \
                bfr[i] = *(const bf16x8*)((const char*)Bs_ +                       \
                          ((((rb << 7) + (kk << 6) + hi4)) ^ sw));                 \
            }                                                                      \
            _Pragma("unroll")                                                      \
            for (int mi = 0; mi < 4; ++mi)                                         \
                _Pragma("unroll")                                                  \
                for (int ni = 0; ni < 4; ++ni)                                     \
                    acc[mi][ni] = __builtin_amdgcn_mfma_f32_16x16x32_bf16(         \
                        af[mi], bfr[ni], acc[mi][ni], 0, 0, 0);                    \
        }                                                                          \
        __syncthreads();                                                           \
        cur_ ^= 1;                                                                 \
    }

// plain TN GEMM: C = scale * A·Bt^T (+relu); ld = full K row-stride (KLOOP may be less)
template <typename OutT, bool RELU, int TA, int TB>
__global__ void __launch_bounds__(256, 2)
gemm_tn(const bf16* __restrict__ A, const bf16* __restrict__ Bt, OutT* __restrict__ C,
        int M, int N, int KLOOP, int ld, long long sA, long long sBt, long long sC,
        float scale) {
    A  += (long long)blockIdx.z * sA;
    Bt += (long long)blockIdx.z * sBt;
    C  += (long long)blockIdx.z * sC;
    GEMM_PROLOGUE_AND_LOOP(A, Bt, KLOOP, ld, TA, TB)
    const int rbase = m0 + wr + (lane >> 4) * 4;
    const int cbase = n0 + wc + lr;
    #pragma unroll
    for (int mi = 0; mi < 4; ++mi)
        #pragma unroll
        for (int ni = 0; ni < 4; ++ni)
            #pragma unroll
            for (int r = 0; r < 4; ++r) {
                float v = acc[mi][ni][r] * scale;
                if (RELU) v = fmaxf(v, 0.0f);
                C[(long long)(rbase + mi * 16 + r) * N + (cbase + ni * 16)] = (OutT)v;
            }
}

// G2 split-K reduce: G2 = bf16(sum of 4 f32 partial planes)
__global__ void g2_reduce(const float* __restrict__ p, bf16* __restrict__ g2) {
    int i = (blockIdx.x * 256 + threadIdx.x) * 4;
    float4 a = *(const float4*)(p + i);
    float4 b = *(const float4*)(p + 1048576 + i);
    float4 c = *(const float4*)(p + 2097152 + i);
    float4 d = *(const float4*)(p + 3145728 + i);
    bf16x4 o = { (bf16)(a.x + b.x + c.x + d.x), (bf16)(a.y + b.y + c.y + d.y),
                 (bf16)(a.z + b.z + c.z + d.z), (bf16)(a.w + b.w + c.w + d.w) };
    *(bf16x4*)(g2 + i) = o;
}

// ---------------- sim GEMM: A = e (bf16, gload dbuf); B = f32 T transposed in-LDS ----------------
// E[n,l] = exp(acc/32) bf16 ; rspart[(b*4+bx)*128 + n] = per-tile row sums
__global__ void __launch_bounds__(256, 2)
gemm_sim_exp(const bf16* __restrict__ A /*e*/, const float* __restrict__ Tg,
             bf16* __restrict__ E, float* __restrict__ rspart) {
    __shared__ char smem[49152];                 // As dbuf 32K + Bs 16K
    __shared__ float scratch[64 * 132];          // f32 transpose scratch
    __shared__ float rs[2][128];
    bf16* AsB = (bf16*)smem;
    bf16* Bs  = (bf16*)(smem + 32768);
    A  += (long long)blockIdx.z * ((long long)Nn * Cc);
    Tg += (long long)blockIdx.z * ((long long)Cc * Ll);
    E  += (long long)blockIdx.z * ((long long)Nn * Ll);
    const int n0 = blockIdx.x * 128;             // l-offset of output tile
    const int t = threadIdx.x, lane = t & 63, w = t >> 6;
    const int wr = (w >> 1) * 64, wc = (w & 1) * 64;
    const int lr = lane & 15, hi4 = (lane >> 4) * 16, sw = (lr & 7) << 4;
    const bf16* gA[4]; int lo[4];
    #pragma unroll
    for (int p = 0; p < 4; ++p) {
        int o = w * 1024 + lane * 16 + p * 4096;
        int row = o >> 7;
        int scol = ((o & 127) ^ ((row & 7) << 4)) >> 1;
        lo[p] = o;
        gA[p] = A + (long long)row * Cc + scol;
    }
    const int s1_rc = t >> 2, s1_l = (t & 3) * 32;   // stage1: c-row, l-chunk base
    const int s2_l = t & 127, s2_ch = (t >> 7) * 8;  // stage2: l-row, c-octet base
    float4 treg[8];
    #pragma unroll
    for (int p = 0; p < 4; ++p) gload_lds16(gA[p], (char*)AsB + lo[p]);
    #pragma unroll
    for (int i = 0; i < 8; ++i)
        treg[i] = *(const float4*)(Tg + (long long)s1_rc * Ll + n0 + s1_l + i * 4);
    f32x4 acc[4][4] = {};
    int cur = 0;
    const int NT = Cc / 64;
    for (int kt = 0; kt < NT; ++kt) {
        if (kt + 1 < NT) {
            #pragma unroll
            for (int p = 0; p < 4; ++p)
                gload_lds16(gA[p] + (kt + 1) * 64, (char*)AsB + (cur ^ 1) * 16384 + lo[p]);
        }
        #pragma unroll
        for (int i = 0; i < 8; ++i)
            *(float4*)&scratch[s1_rc * 132 + s1_l + i * 4] = treg[i];
        __syncthreads();
        if (kt + 1 < NT) {
            #pragma unroll
            for (int i = 0; i < 8; ++i)
                treg[i] = *(const float4*)(Tg + (long long)((kt + 1) * 64 + s1_rc) * Ll
                                           + n0 + s1_l + i * 4);
        }
        #pragma unroll
        for (int g = 0; g < 4; ++g) {
            int c0 = s2_ch + g * 16;
            bf16x8 bv;
            #pragma unroll
            for (int j = 0; j < 8; ++j) bv[j] = (bf16)scratch[(c0 + j) * 132 + s2_l];
            *(bf16x8*)((char*)Bs + ((s2_l * 128 + c0 * 2) ^ ((s2_l & 7) << 4))) = bv;
        }
        __syncthreads();
        const bf16* As_ = AsB + cur * 8192;
        #pragma unroll
        for (int kk = 0; kk < 2; ++kk) {
            bf16x8 af[4], bfr[4];
            #pragma unroll
            for (int i = 0; i < 4; ++i) {
                int ra = wr + i * 16 + lr;
                int rb = wc + i * 16 + lr;
                af[i]  = *(const bf16x8*)((const char*)As_ + (((ra << 7) + (kk << 6) + hi4) ^ sw));
                bfr[i] = *(const bf16x8*)((const char*)Bs  + (((rb << 7) + (kk << 6) + hi4) ^ sw));
            }
            #pragma unroll
            for (int mi = 0; mi < 4; ++mi)
                #pragma unroll
                for (int ni = 0; ni < 4; ++ni)
                    acc[mi][ni] = __builtin_amdgcn_mfma_f32_16x16x32_bf16(
                        af[mi], bfr[ni], acc[mi][ni], 0, 0, 0);
        }
        __syncthreads();
        cur ^= 1;
    }
    const int rbase = wr + (lane >> 4) * 4;
    const int cbase = n0 + wc + lr;
    float psum[4][4];
    #pragma unroll
    for (int mi = 0; mi < 4; ++mi)
        #pragma unroll
        for (int r = 0; r < 4; ++r) psum[mi][r] = 0.f;
    #pragma unroll
    for (int mi = 0; mi < 4; ++mi)
        #pragma unroll
        for (int ni = 0; ni < 4; ++ni)
            #pragma unroll
            for (int r = 0; r < 4; ++r) {
                float ev = __expf(acc[mi][ni][r] * 0.03125f);
                E[(long long)(rbase + mi * 16 + r) * Ll + (cbase + ni * 16)] = (bf16)ev;
                psum[mi][r] += ev;
            }
    #pragma unroll
    for (int mi = 0; mi < 4; ++mi)
        #pragma unroll
        for (int r = 0; r < 4; ++r) {
            float v = psum[mi][r];
            v += __shfl_xor(v, 1); v += __shfl_xor(v, 2);
            v += __shfl_xor(v, 4); v += __shfl_xor(v, 8);
            psum[mi][r] = v;
        }
    if (lr == 0) {
        #pragma unroll
        for (int mi = 0; mi < 4; ++mi)
            #pragma unroll
            for (int r = 0; r < 4; ++r)
                rs[wc ? 1 : 0][wr + (lane >> 4) * 4 + mi * 16 + r] = psum[mi][r];
    }
    __syncthreads();
    if (t < 128)
        rspart[((long long)blockIdx.z * 4 + blockIdx.x) * 128 + t] = rs[0][t] + rs[1][t];
}

// ---------------- u GEMM: A = E (gload dbuf); B = f32 T natural-orientation reg-staged ----------------
// u[n,c] = (E·T^T over l)[n,c] / rowsum[n]
__global__ void __launch_bounds__(256, 2)
gemm_u_scaled(const bf16* __restrict__ A /*E*/, const float* __restrict__ Tg,
              bf16* __restrict__ C, const float* __restrict__ rspart) {
    __shared__ char smem[49152];                 // As dbuf 32K + Bs 16K
    bf16* AsB = (bf16*)smem;
    bf16* Bs  = (bf16*)(smem + 32768);
    A  += (long long)blockIdx.z * ((long long)Nn * Ll);
    Tg += (long long)blockIdx.z * ((long long)Cc * Ll);
    C  += (long long)blockIdx.z * ((long long)Nn * Cc);
    const float* rp = rspart + (long long)blockIdx.z * 512;
    const int n0 = blockIdx.x * 128;             // c-offset of output tile
    const int t = threadIdx.x, lane = t & 63, w = t >> 6;
    const int wr = (w >> 1) * 64, wc = (w & 1) * 64;
    const int lr = lane & 15, hi4 = (lane >> 4) * 16, sw = (lr & 7) << 4;
    const bf16* gA[4]; int lo[4];
    #pragma unroll
    for (int p = 0; p < 4; ++p) {
        int o = w * 1024 + lane * 16 + p * 4096;
        int row = o >> 7;
        int scol = ((o & 127) ^ ((row & 7) << 4)) >> 1;
        lo[p] = o;
        gA[p] = A + (long long)row * Ll + scol;
    }
    const int s_c = t >> 1, s_half = (t & 1) * 32;   // B-stage: c-row, l-half
    float4 treg[8];
    #pragma unroll
    for (int p = 0; p < 4; ++p) gload_lds16(gA[p], (char*)AsB + lo[p]);
    #pragma unroll
    for (int i = 0; i < 8; ++i)
        treg[i] = *(const float4*)(Tg + (long long)(n0 + s_c) * Ll + s_half + i * 4);
    f32x4 acc[4][4] = {};
    int cur = 0;
    const int NT = Ll / 64;
    for (int kt = 0; kt < NT; ++kt) {
        if (kt + 1 < NT) {
            #pragma unroll
            for (int p = 0; p < 4; ++p)
                gload_lds16(gA[p] + (kt + 1) * 64, (char*)AsB + (cur ^ 1) * 16384 + lo[p]);
        }
        __syncthreads();   // prior MFMA's Bs reads complete before overwrite
        #pragma unroll
        for (int q = 0; q < 4; ++q) {
            bf16x8 bv;
            #pragma unroll
            for (int j = 0; j < 4; ++j) {
                bv[j]     = (bf16)((const float*)&treg[q * 2])[j];
                bv[4 + j] = (bf16)((const float*)&treg[q * 2 + 1])[j];
            }
            *(bf16x8*)((char*)Bs + ((s_c * 128 + (s_half + q * 8) * 2) ^ ((s_c & 7) << 4))) = bv;
        }
        if (kt + 1 < NT) {
            #pragma unroll
            for (int i = 0; i < 8; ++i)
                treg[i] = *(const float4*)(Tg + (long long)(n0 + s_c) * Ll
                                           + (kt + 1) * 64 + s_half + i * 4);
        }
        __syncthreads();
        const bf16* As_ = AsB + cur * 8192;
        #pragma unroll
        for (int kk = 0; kk < 2; ++kk) {
            bf16x8 af[4], bfr[4];
            #pragma unroll
            for (int i = 0; i < 4; ++i) {
                int ra = wr + i * 16 + lr;
                int rb = wc + i * 16 + lr;
                af[i]  = *(const bf16x8*)((const char*)As_ + (((ra << 7) + (kk << 6) + hi4) ^ sw));
                bfr[i] = *(const bf16x8*)((const char*)Bs  + (((rb << 7) + (kk << 6) + hi4) ^ sw));
            }
            #pragma unroll
            for (int mi = 0; mi < 4; ++mi)
                #pragma unroll
                for (int ni = 0; ni < 4; ++ni)
                    acc[mi][ni] = __builtin_amdgcn_mfma_f32_16x16x32_bf16(
                        af[mi], bfr[ni], acc[mi][ni], 0, 0, 0);
        }
        cur ^= 1;
    }
    const int rbase = wr + (lane >> 4) * 4;
    const int cbase = n0 + wc + lr;
    #pragma unroll
    for (int mi = 0; mi < 4; ++mi)
        #pragma unroll
        for (int r = 0; r < 4; ++r) {
            int row = rbase + mi * 16 + r;
            float inv = 1.f / (rp[row] + rp[128 + row] + rp[256 + row] + rp[384 + row]);
            #pragma unroll
            for (int ni = 0; ni < 4; ++ni)
                C[(long long)row * Cc + (cbase + ni * 16)] = (bf16)(acc[mi][ni][r] * inv);
        }
}

// ctx GEMM + LN1 residual/stats epilogue (Z1 bf16):
__global__ void __launch_bounds__(256, 2)
gemm_ctx_ln1(const bf16* __restrict__ A /*Wv*/, const bf16* __restrict__ Bt /*u*/,
             const float* __restrict__ X, bf16* __restrict__ Z1, float* __restrict__ partials,
             int K, long long sBt) {
    const int N = Nn;
    Bt += (long long)blockIdx.z * sBt;
    X  += (long long)blockIdx.z * PLANE;
    Z1 += (long long)blockIdx.z * PLANE;
    GEMM_PROLOGUE_AND_LOOP(A, Bt, K, K, 0, 0)
    const int rbase = m0 + wr + (lane >> 4) * 4;
    const int cbase = n0 + wc + lr;
    float s = 0.f, ss = 0.f;
    #pragma unroll
    for (int mi = 0; mi < 4; ++mi)
        #pragma unroll
        for (int ni = 0; ni < 4; ++ni)
            #pragma unroll
            for (int r = 0; r < 4; ++r) {
                long long idx = (long long)(rbase + mi * 16 + r) * N + (cbase + ni * 16);
                float zv = acc[mi][ni][r] + X[idx];
                Z1[idx] = (bf16)zv;
                s += zv; ss += zv * zv;
            }
    #pragma unroll
    for (int off = 32; off; off >>= 1) { s += __shfl_xor(s, off); ss += __shfl_xor(ss, off); }
    __shared__ float red[8];
    if (lane == 0) { red[w] = s; red[4 + w] = ss; }
    __syncthreads();
    if (t == 0) {
        float S = red[0] + red[1] + red[2] + red[3];
        float SS = red[4] + red[5] + red[6] + red[7];
        float* p = partials + ((long long)blockIdx.z * 8 + blockIdx.y) * 2;
        p[0] = S; p[1] = SS;
    }
}

// FFN GEMM + LN2 epilogue (Xout recomputed from bf16 Z1 + pp1; Z2 bf16):
__global__ void __launch_bounds__(256, 2)
gemm_ffn_ln2(const bf16* __restrict__ A /*hT*/, const bf16* __restrict__ Bt /*Wf2*/,
             const bf16* __restrict__ Z1, const float* __restrict__ pp1,
             const float* __restrict__ gamma, const float* __restrict__ beta,
             bf16* __restrict__ Z2, float* __restrict__ partials,
             int K, long long sA) {
    A  += (long long)blockIdx.z * sA;
    Z1 += (long long)blockIdx.z * PLANE;
    Z2 += (long long)blockIdx.z * PLANE;
    float S1 = 0.f, SS1 = 0.f;
    #pragma unroll
    for (int j = 0; j < 8; ++j) {
        S1  += pp1[((long long)blockIdx.z * 8 + j) * 2];
        SS1 += pp1[((long long)blockIdx.z * 8 + j) * 2 + 1];
    }
    const float mean1 = S1 * INV_PLANE;
    const float rstd1 = rsqrtf(SS1 * INV_PLANE - mean1 * mean1 + 1e-5f);
    GEMM_PROLOGUE_AND_LOOP(A, Bt, K, K, 0, 0)
    const int rbase = m0 + wr + (lane >> 4) * 4;
    const int cbase = n0 + wc + lr;
    float s = 0.f, ss = 0.f;
    #pragma unroll
    for (int mi = 0; mi < 4; ++mi)
        #pragma unroll
        for (int ni = 0; ni < 4; ++ni) {
            long long a = (long long)(cbase + ni * 16) * Nn + rbase + mi * 16;
            bf16x4 z1v = *(const bf16x4*)(Z1 + a);
            float4 g  = *(const float4*)(gamma + a);
            float4 be = *(const float4*)(beta + a);
            float x0 = ((float)z1v[0] - mean1) * rstd1 * g.x + be.x;
            float x1 = ((float)z1v[1] - mean1) * rstd1 * g.y + be.y;
            float x2 = ((float)z1v[2] - mean1) * rstd1 * g.z + be.z;
            float x3 = ((float)z1v[3] - mean1) * rstd1 * g.w + be.w;
            float z0 = acc[mi][ni][0] + x0, z1 = acc[mi][ni][1] + x1;
            float z2 = acc[mi][ni][2] + x2, z3 = acc[mi][ni][3] + x3;
            bf16x4 zo = { (bf16)z0, (bf16)z1, (bf16)z2, (bf16)z3 };
            *(bf16x4*)(Z2 + a) = zo;
            s  += z0 + z1 + z2 + z3;
            ss += z0 * z0 + z1 * z1 + z2 * z2 + z3 * z3;
        }
    #pragma unroll
    for (int off = 32; off; off >>= 1) { s += __shfl_xor(s, off); ss += __shfl_xor(ss, off); }
    __shared__ float red[8];
    if (lane == 0) { red[w] = s; red[4 + w] = ss; }
    __syncthreads();
    if (t == 0) {
        float S = red[0] + red[1] + red[2] + red[3];
        float SS = red[4] + red[5] + red[6] + red[7];
        float* p = partials + ((long long)blockIdx.z * 8 + blockIdx.x) * 2;
        p[0] = S; p[1] = SS;
    }
}

// ---------------- LN1 normalize + tiled transposed bf16 output ----------------
__global__ void ln1_norm_transpose(const bf16* __restrict__ Z1, const float* __restrict__ partials,
                                   const float* __restrict__ gamma, const float* __restrict__ beta,
                                   bf16* __restrict__ XoutT) {
    int b = blockIdx.z;
    float S = 0.f, SS = 0.f;
    #pragma unroll
    for (int j = 0; j < 8; ++j) {
        S  += partials[((long long)b * 8 + j) * 2];
        SS += partials[((long long)b * 8 + j) * 2 + 1];
    }
    float mean = S * INV_PLANE;
    float rstd = rsqrtf(SS * INV_PLANE - mean * mean + 1e-5f);
    __shared__ float tile[64][65];
    long long base = (long long)b * PLANE;
    int n0 = blockIdx.x * 64, c0 = blockIdx.y * 64;
    int t = threadIdx.x;
    int rl = t >> 4, sc = (t & 15) * 4;
    #pragma unroll
    for (int p = 0; p < 4; ++p) {
        int r = p * 16 + rl;
        long long idx = (long long)(c0 + r) * Nn + n0 + sc;
        bf16x4 z  = *(const bf16x4*)(Z1 + base + idx);
        float4 g  = *(const float4*)(gamma + idx);
        float4 be = *(const float4*)(beta + idx);
        float4 o = {((float)z[0] - mean) * rstd * g.x + be.x,
                    ((float)z[1] - mean) * rstd * g.y + be.y,
                    ((float)z[2] - mean) * rstd * g.z + be.z,
                    ((float)z[3] - mean) * rstd * g.w + be.w};
        *(float4*)&tile[r][sc] = o;
    }
    __syncthreads();
    long long tb = ((long long)(n0 >> 6) * (Cc >> 6) + (c0 >> 6)) * 4096;
    int sb = t >> 3, rg = (t & 7) * 8;
    #pragma unroll
    for (int p = 0; p < 2; ++p) {
        int n = sb + p * 32;
        bf16x8 o;
        #pragma unroll
        for (int j = 0; j < 8; ++j) o[j] = (bf16)tile[rg + j][n];
        *(bf16x8*)(XoutT + base + tb + n * 64 + rg) = o;
    }
}

// ---------------- final LN ----------------
__global__ void ln2_final(const bf16* __restrict__ Z2, const float* __restrict__ partials,
                          const float* __restrict__ gamma, const float* __restrict__ beta,
                          float* __restrict__ out) {
    int b = blockIdx.y;
    float S = 0.f, SS = 0.f;
    #pragma unroll
    for (int j = 0; j < 8; ++j) {
        S  += partials[((long long)b * 8 + j) * 2];
        SS += partials[((long long)b * 8 + j) * 2 + 1];
    }
    float mean = S * INV_PLANE;
    float rstd = rsqrtf(SS * INV_PLANE - mean * mean + 1e-5f);
    long long base = (long long)b * PLANE;
    int i = (blockIdx.x * 256 + threadIdx.x) * 8;
    bf16x8 z = *(const bf16x8*)(Z2 + base + i);
    #pragma unroll
    for (int h = 0; h < 2; ++h) {
        float4 g  = *(const float4*)(gamma + i + h * 4);
        float4 be = *(const float4*)(beta + i + h * 4);
        float4 o = {((float)z[h * 4 + 0] - mean) * rstd * g.x + be.x,
                    ((float)z[h * 4 + 1] - mean) * rstd * g.y + be.y,
                    ((float)z[h * 4 + 2] - mean) * rstd * g.z + be.z,
                    ((float)z[h * 4 + 3] - mean) * rstd * g.w + be.w};
        *(float4*)(out + base + i + h * 4) = o;
    }
}

extern "C" void kernel_launch(void* const* d_in, const int* in_sizes, int n_in,
                              void* d_out, int out_size, void* d_ws, size_t ws_size,
                              hipStream_t stream) {
    const float* X   = (const float*)d_in[0];
    const float* T   = (const float*)d_in[1];
    const float* Wq  = (const float*)d_in[2];
    const float* Wk  = (const float*)d_in[3];
    const float* Wv  = (const float*)d_in[4];
    const float* Wf1 = (const float*)d_in[5];
    const float* Wf2 = (const float*)d_in[6];
    const float* gamma = (const float*)d_in[7];
    const float* beta  = (const float*)d_in[8];
    float* out = (float*)d_out;
    char* ws = (char*)d_ws;
    const size_t MB = 1ull << 20;

    bf16* WvB  = (bf16*)(ws + 0 * MB);
    bf16* Wf1B = (bf16*)(ws + 2 * MB);
    bf16* Wf2B = (bf16*)(ws + 4 * MB);
    bf16* WqT  = (bf16*)(ws + 6 * MB);
    bf16* WkT  = (bf16*)(ws + 8 * MB);
    bf16* G2   = (bf16*)(ws + 10 * MB);
    bf16* Xt   = (bf16*)(ws + 12 * MB);    // 16 MB tiled
    bf16* Z1   = (bf16*)(ws + 28 * MB);    // 16 MB
    bf16* XoutT= (bf16*)(ws + 44 * MB);    // 16 MB tiled
    bf16* hT   = (bf16*)(ws + 60 * MB);    // 16 MB
    bf16* e    = (bf16*)(ws + 76 * MB);    // 16 MB
    bf16* Z2   = (bf16*)(ws + 92 * MB);    // 16 MB
    bf16* E    = (bf16*)(ws + 108 * MB);   // 8 MB
    bf16* u    = (bf16*)(ws + 116 * MB);   // 16 MB
    float* G2p = (float*)(ws + 132 * MB);  // 16 MB (4 f32 planes)
    float* pp1 = (float*)(ws + 148 * MB);
    float* pp2 = (float*)(ws + 148 * MB + 65536);
    float* rsp = (float*)(ws + 149 * MB);

    dim3 blk256(256);

    // 1. prep: weight casts + Wq/Wk transposes + Xt
    prep_all<<<dim3(5632), blk256, 0, stream>>>(
        Wv, Wf1, Wf2, Wq, Wk, X, WvB, Wf1B, Wf2B, WqT, WkT, Xt);

    // 2. G2 split-K=4: partials then reduce
    gemm_tn<float, false, 1, 1><<<dim3(8, 8, 4), blk256, 0, stream>>>(
        WkT, WqT, G2p, Cc, Cc, 256, Cc, 16384, 16384, 1048576, 1.f);
    g2_reduce<<<dim3(1024), blk256, 0, stream>>>(G2p, G2);

    // 3. e = Xt·G2^T  [128,1024,1024] (A tiled)
    gemm_tn<bf16, false, 1, 0><<<dim3(8, 1, Bb), blk256, 0, stream>>>(
        Xt, G2, e, Nn, Cc, Cc, Cc, (long long)Nn * Cc, 0, (long long)Nn * Cc, 1.f);
    // 4. E = exp(sim/32) + rowsum partials; B = f32 T transposed in-LDS
    gemm_sim_exp<<<dim3(4, 1, Bb), blk256, 0, stream>>>(e, T, E, rsp);
    // 5. u = (E·T over l)/rowsum; B = f32 T natural orientation
    gemm_u_scaled<<<dim3(8, 1, Bb), blk256, 0, stream>>>(E, T, u, rsp);
    // 6. Z1 = Wv·u^T + X + stats
    gemm_ctx_ln1<<<dim3(1, 8, Bb), blk256, 0, stream>>>(
        WvB, u, X, Z1, pp1, Cc, (long long)Nn * Cc);
    // 7. LN1 -> XoutT tiled
    ln1_norm_transpose<<<dim3(Nn / 64, Cc / 64, Bb), blk256, 0, stream>>>(
        Z1, pp1, gamma, beta, XoutT);
    // 8. hT = relu(XoutT·Wf1^T) (A tiled)
    gemm_tn<bf16, true, 1, 0><<<dim3(8, 1, Bb), blk256, 0, stream>>>(
        XoutT, Wf1B, hT, Nn, Cc, Cc, Cc, (long long)Nn * Cc, 0, (long long)Nn * Cc, 1.f);
    // 9. Z2 = transpose(hT·Wf2^T) + LN1(Z1) + stats
    gemm_ffn_ln2<<<dim3(8, 1, Bb), blk256, 0, stream>>>(
        hT, Wf2B, Z1, pp1, gamma, beta, Z2, pp2, Cc, (long long)Nn * Cc);
    // 10. LN2 -> out
    ln2_final<<<dim3(64, Bb), blk256, 0, stream>>>(Z2, pp2, gamma, beta, out);
}

// Round 9
// 279.765 us; speedup vs baseline: 1.0482x; 1.0209x over previous
//
#include <hip/hip_runtime.h>

// Transformer decoder block, MI355X gfx950. Round 9: sim kernel rebuilt —
// bf16 scratch [64][130] (16.6KB), single-buffered As, 2 barriers/kt,
// LDS 50.4KB -> 3 blocks/CU (was 114KB -> 1 block/CU). All else = round 8.
//
// Dataflow:
//   WqT,WkT = transpose(Wq,Wk) bf16 [tiled] ; G2 = WkT·WqT^T (split-K)
//   Xt  = transpose(X_in) bf16 (B,N,C) [tiled]
//   e   = Xt · G2^T             (B,N,C)  bf16
//   E   = exp((e·T^T-staged)/32)(B,N,L)  bf16 + row-sum partials
//   u   = (E · T-staged) / rowsum (B,N,C) bf16
//   Z1  = Wv · u^T + X_in       (B,C,N)  bf16 + stats pp1
//   XoutT = LN(Z1) bf16 (N,C) [tiled]
//   hT  = relu(XoutT · Wf1^T)   (B,N,C)  bf16
//   Z2  = transpose(hT·Wf2^T) + LN(Z1)   bf16 + pp2
//   out = LN(Z2) f32

using bf16   = __bf16;
using bf16x4 = __attribute__((ext_vector_type(4))) __bf16;
using bf16x8 = __attribute__((ext_vector_type(8))) __bf16;
using f32x4  = __attribute__((ext_vector_type(4))) float;

static constexpr int  Bb = 64;
static constexpr int  Cc = 1024;
static constexpr int  Nn = 128;
static constexpr int  Ll = 512;
static constexpr long long PLANE = (long long)Cc * Nn;
static constexpr float INV_PLANE = 1.0f / 131072.0f;

__device__ __forceinline__ void gload_lds16(const void* g, void* l) {
    __builtin_amdgcn_global_load_lds(
        (__attribute__((address_space(1))) void*)g,
        (__attribute__((address_space(3))) void*)l,
        16, 0, 0);
}

// ---------------- prep: weight casts + Wq/Wk transposes + Xt (tiled) ----------------
__global__ void __launch_bounds__(256)
prep_all(const float* __restrict__ Wv, const float* __restrict__ Wf1,
         const float* __restrict__ Wf2, const float* __restrict__ Wq,
         const float* __restrict__ Wk, const float* __restrict__ X,
         bf16* __restrict__ WvB, bf16* __restrict__ Wf1B, bf16* __restrict__ Wf2B,
         bf16* __restrict__ WqT, bf16* __restrict__ WkT, bf16* __restrict__ Xt) {
    __shared__ float tile[64][65];
    const int bx = blockIdx.x;
    const int t  = threadIdx.x;
    if (bx < 3072) {
        const float* in = bx < 1024 ? Wv : (bx < 2048 ? Wf1 : Wf2);
        bf16* out       = bx < 1024 ? WvB : (bx < 2048 ? Wf1B : Wf2B);
        int i = (bx & 1023) * 256 + t;
        float4 v = reinterpret_cast<const float4*>(in)[i];
        bf16x4 o = { (bf16)v.x, (bf16)v.y, (bf16)v.z, (bf16)v.w };
        reinterpret_cast<bf16x4*>(out)[i] = o;
        return;
    }
    const float* in; bf16* outT;
    int R, S, bxx, byy, bz = 0;
    if (bx < 3584) {
        int j = bx - 3072;
        in = (j >= 256) ? Wk : Wq; outT = (j >= 256) ? WkT : WqT;
        R = Cc; S = Cc; j &= 255; bxx = j & 15; byy = j >> 4;
    } else {
        int j = bx - 3584; bz = j >> 5; j &= 31;
        bxx = j & 1; byy = j >> 1; in = X; outT = Xt; R = Cc; S = Nn;
    }
    long long plane = (long long)R * S;
    in   += (long long)bz * plane;
    outT += (long long)bz * plane;
    int s0 = bxx * 64, r0 = byy * 64;
    int rl = t >> 4, sc = (t & 15) * 4;
    #pragma unroll
    for (int p = 0; p < 4; ++p) {
        int r = p * 16 + rl;
        float4 v = *(const float4*)(in + (long long)(r0 + r) * S + s0 + sc);
        *(float4*)&tile[r][sc] = v;
    }
    __syncthreads();
    long long tb = ((long long)(s0 >> 6) * (R >> 6) + (r0 >> 6)) * 4096;
    int sb = t >> 3, rg = (t & 7) * 8;
    #pragma unroll
    for (int p = 0; p < 2; ++p) {
        int s = sb + p * 32;
        bf16x8 o;
        #pragma unroll
        for (int j = 0; j < 8; ++j) o[j] = (bf16)tile[rg + j][s];
        *(bf16x8*)(outT + tb + s * 64 + rg) = o;
    }
}

// ---------------- generic TN GEMM core (gload-staged both sides) ----------------
#define GEMM_PROLOGUE_AND_LOOP(A_, Bt_, KLOOP_, LD_, TA_, TB_)                     \
    __shared__ bf16 As[2][128 * 64];                                               \
    __shared__ bf16 Bs[2][128 * 64];                                               \
    const int n0   = blockIdx.x * 128;                                             \
    const int m0   = blockIdx.y * 128;                                             \
    const int t    = threadIdx.x;                                                  \
    const int lane = t & 63;                                                       \
    const int w    = t >> 6;                                                       \
    const int wr   = (w >> 1) * 64;                                                \
    const int wc   = (w & 1) * 64;                                                 \
    const int lr   = lane & 15;                                                    \
    const int hi4  = (lane >> 4) * 16;                                             \
    const int sw   = (lr & 7) << 4;                                                \
    const int stepA_ = (TA_) ? 4096 : 64;                                          \
    const int stepB_ = (TB_) ? 4096 : 64;                                          \
    const bf16* gA[4]; const bf16* gB[4]; int lo[4];                               \
    _Pragma("unroll")                                                              \
    for (int p = 0; p < 4; ++p) {                                                  \
        int o = w * 1024 + lane * 16 + p * 4096;                                   \
        int row = o >> 7;                                                          \
        int scol = ((o & 127) ^ ((row & 7) << 4)) >> 1;                            \
        lo[p] = o;                                                                 \
        int ra = m0 + row, rb = n0 + row;                                          \
        gA[p] = (TA_) ? A_ + ((long long)(ra >> 6) * (LD_ >> 6)) * 4096            \
                           + (ra & 63) * 64 + scol                                 \
                      : A_ + (long long)ra * LD_ + scol;                           \
        gB[p] = (TB_) ? Bt_ + ((long long)(rb >> 6) * (LD_ >> 6)) * 4096           \
                            + (rb & 63) * 64 + scol                                \
                      : Bt_ + (long long)rb * LD_ + scol;                          \
    }                                                                              \
    f32x4 acc[4][4] = {};                                                          \
    const int NT_ = KLOOP_ / 64;                                                   \
    _Pragma("unroll")                                                              \
    for (int p = 0; p < 4; ++p) gload_lds16(gA[p], (char*)As[0] + lo[p]);          \
    _Pragma("unroll")                                                              \
    for (int p = 0; p < 4; ++p) gload_lds16(gB[p], (char*)Bs[0] + lo[p]);          \
    __syncthreads();                                                               \
    int cur_ = 0;                                                                  \
    for (int kt = 0; kt < NT_; ++kt) {                                             \
        if (kt + 1 < NT_) {                                                        \
            _Pragma("unroll")                                                      \
            for (int p = 0; p < 4; ++p)                                            \
                gload_lds16(gA[p] + (long long)(kt + 1) * stepA_,                  \
                            (char*)As[cur_ ^ 1] + lo[p]);                          \
            _Pragma("unroll")                                                      \
            for (int p = 0; p < 4; ++p)                                            \
                gload_lds16(gB[p] + (long long)(kt + 1) * stepB_,                  \
                            (char*)Bs[cur_ ^ 1] + lo[p]);                          \
        }                                                                          \
        const bf16* As_ = As[cur_]; const bf16* Bs_ = Bs[cur_];                    \
        _Pragma("unroll")                                                          \
        for (int kk = 0; kk < 2; ++kk) {                                           \
            bf16x8 af[4], bfr[4];                                                  \
            _Pragma("unroll")                                                      \
            for (int i = 0; i < 4; ++i) {                                          \
                int ra = wr + i * 16 + lr;                                         \
                int rb = wc + i * 16 + lr;                                         \
                af[i]  = *(const bf16x8*)((const char*)As_ +                       \
                          ((((ra << 7) + (kk << 6) + hi4)) ^ sw));                 \
                bfr[i] = *(const bf16x8*)((const char*)Bs_ +                       \
                          ((((rb << 7) + (kk << 6) + hi4)) ^ sw));                 \
            }                                                                      \
            _Pragma("unroll")                                                      \
            for (int mi = 0; mi < 4; ++mi)                                         \
                _Pragma("unroll")                                                  \
                for (int ni = 0; ni < 4; ++ni)                                     \
                    acc[mi][ni] = __builtin_amdgcn_mfma_f32_16x16x32_bf16(         \
                        af[mi], bfr[ni], acc[mi][ni], 0, 0, 0);                    \
        }                                                                          \
        __syncthreads();                                                           \
        cur_ ^= 1;                                                                 \
    }

template <typename OutT, bool RELU, int TA, int TB>
__global__ void __launch_bounds__(256, 2)
gemm_tn(const bf16* __restrict__ A, const bf16* __restrict__ Bt, OutT* __restrict__ C,
        int M, int N, int KLOOP, int ld, long long sA, long long sBt, long long sC,
        float scale) {
    A  += (long long)blockIdx.z * sA;
    Bt += (long long)blockIdx.z * sBt;
    C  += (long long)blockIdx.z * sC;
    GEMM_PROLOGUE_AND_LOOP(A, Bt, KLOOP, ld, TA, TB)
    const int rbase = m0 + wr + (lane >> 4) * 4;
    const int cbase = n0 + wc + lr;
    #pragma unroll
    for (int mi = 0; mi < 4; ++mi)
        #pragma unroll
        for (int ni = 0; ni < 4; ++ni)
            #pragma unroll
            for (int r = 0; r < 4; ++r) {
                float v = acc[mi][ni][r] * scale;
                if (RELU) v = fmaxf(v, 0.0f);
                C[(long long)(rbase + mi * 16 + r) * N + (cbase + ni * 16)] = (OutT)v;
            }
}

__global__ void g2_reduce(const float* __restrict__ p, bf16* __restrict__ g2) {
    int i = (blockIdx.x * 256 + threadIdx.x) * 4;
    float4 a = *(const float4*)(p + i);
    float4 b = *(const float4*)(p + 1048576 + i);
    float4 c = *(const float4*)(p + 2097152 + i);
    float4 d = *(const float4*)(p + 3145728 + i);
    bf16x4 o = { (bf16)(a.x + b.x + c.x + d.x), (bf16)(a.y + b.y + c.y + d.y),
                 (bf16)(a.z + b.z + c.z + d.z), (bf16)(a.w + b.w + c.w + d.w) };
    *(bf16x4*)(g2 + i) = o;
}

// ---------------- sim GEMM v2: A = e (single-buf gload); B = f32 T -> bf16 scratch
//                  transpose -> swizzled Bs. LDS 50.4KB -> 3 blocks/CU. ----------------
__global__ void __launch_bounds__(256, 3)
gemm_sim_exp(const bf16* __restrict__ A /*e*/, const float* __restrict__ Tg,
             bf16* __restrict__ E, float* __restrict__ rspart) {
    __shared__ char smem[50432];
    bf16*  Asb = (bf16*)smem;                  // 16384 B
    bf16*  Bs  = (bf16*)(smem + 16384);        // 16384 B
    bf16*  scr = (bf16*)(smem + 32768);        // [64][130] = 16640 B
    float* rs  = (float*)(smem + 49408);       // [2][128]  = 1024 B
    A  += (long long)blockIdx.z * ((long long)Nn * Cc);
    Tg += (long long)blockIdx.z * ((long long)Cc * Ll);
    E  += (long long)blockIdx.z * ((long long)Nn * Ll);
    const int n0 = blockIdx.x * 128;             // l-offset of output tile
    const int t = threadIdx.x, lane = t & 63, w = t >> 6;
    const int wr = (w >> 1) * 64, wc = (w & 1) * 64;
    const int lr = lane & 15, hi4 = (lane >> 4) * 16, sw = (lr & 7) << 4;
    const bf16* gA[4]; int lo[4];
    #pragma unroll
    for (int p = 0; p < 4; ++p) {
        int o = w * 1024 + lane * 16 + p * 4096;
        int row = o >> 7;
        int scol = ((o & 127) ^ ((row & 7) << 4)) >> 1;
        lo[p] = o;
        gA[p] = A + (long long)row * Cc + scol;
    }
    const int s1_rc = t >> 2, s1_l = (t & 3) * 32;   // stage1: c-row, l-chunk base
    const int s2_l = t & 127, s2_ch = (t >> 7) * 8;  // stage2: l-row, c-octet base
    float4 treg[8];
    #pragma unroll
    for (int i = 0; i < 8; ++i)
        treg[i] = *(const float4*)(Tg + (long long)s1_rc * Ll + n0 + s1_l + i * 4);
    f32x4 acc[4][4] = {};
    const int NT = Cc / 64;
    for (int kt = 0; kt < NT; ++kt) {
        // scratch write: f32 treg -> bf16, [64][130] pad (conflict-free)
        #pragma unroll
        for (int i = 0; i < 8; ++i) {
            float4 v = treg[i];
            bf16x4 o = { (bf16)v.x, (bf16)v.y, (bf16)v.z, (bf16)v.w };
            *(bf16x4*)(scr + s1_rc * 130 + s1_l + i * 4) = o;
        }
        __syncthreads();   // B1: scratch visible; prior MFMA (As/Bs reads) done
        // As gloads for THIS kt (drained at B2)
        #pragma unroll
        for (int p = 0; p < 4; ++p) gload_lds16(gA[p] + kt * 64, (char*)Asb + lo[p]);
        // Bs build: read scratch columns (2-way free), pack, swizzled b128 write
        #pragma unroll
        for (int g = 0; g < 4; ++g) {
            int c0 = s2_ch + g * 16;
            bf16x8 bv;
            #pragma unroll
            for (int j = 0; j < 8; ++j) bv[j] = scr[(c0 + j) * 130 + s2_l];
            *(bf16x8*)((char*)Bs + ((s2_l * 128 + c0 * 2) ^ ((s2_l & 7) << 4))) = bv;
        }
        // prefetch next T chunk
        if (kt + 1 < NT) {
            #pragma unroll
            for (int i = 0; i < 8; ++i)
                treg[i] = *(const float4*)(Tg + (long long)((kt + 1) * 64 + s1_rc) * Ll
                                           + n0 + s1_l + i * 4);
        }
        __syncthreads();   // B2: Bs visible + As gloads drained
        #pragma unroll
        for (int kk = 0; kk < 2; ++kk) {
            bf16x8 af[4], bfr[4];
            #pragma unroll
            for (int i = 0; i < 4; ++i) {
                int ra = wr + i * 16 + lr;
                int rb = wc + i * 16 + lr;
                af[i]  = *(const bf16x8*)((const char*)Asb + (((ra << 7) + (kk << 6) + hi4) ^ sw));
                bfr[i] = *(const bf16x8*)((const char*)Bs  + (((rb << 7) + (kk << 6) + hi4) ^ sw));
            }
            #pragma unroll
            for (int mi = 0; mi < 4; ++mi)
                #pragma unroll
                for (int ni = 0; ni < 4; ++ni)
                    acc[mi][ni] = __builtin_amdgcn_mfma_f32_16x16x32_bf16(
                        af[mi], bfr[ni], acc[mi][ni], 0, 0, 0);
        }
    }
    const int rbase = wr + (lane >> 4) * 4;
    const int cbase = n0 + wc + lr;
    float psum[4][4];
    #pragma unroll
    for (int mi = 0; mi < 4; ++mi)
        #pragma unroll
        for (int r = 0; r < 4; ++r) psum[mi][r] = 0.f;
    #pragma unroll
    for (int mi = 0; mi < 4; ++mi)
        #pragma unroll
        for (int ni = 0; ni < 4; ++ni)
            #pragma unroll
            for (int r = 0; r < 4; ++r) {
                float ev = __expf(acc[mi][ni][r] * 0.03125f);
                E[(long long)(rbase + mi * 16 + r) * Ll + (cbase + ni * 16)] = (bf16)ev;
                psum[mi][r] += ev;
            }
    #pragma unroll
    for (int mi = 0; mi < 4; ++mi)
        #pragma unroll
        for (int r = 0; r < 4; ++r) {
            float v = psum[mi][r];
            v += __shfl_xor(v, 1); v += __shfl_xor(v, 2);
            v += __shfl_xor(v, 4); v += __shfl_xor(v, 8);
            psum[mi][r] = v;
        }
    __syncthreads();
    if (lr == 0) {
        #pragma unroll
        for (int mi = 0; mi < 4; ++mi)
            #pragma unroll
            for (int r = 0; r < 4; ++r)
                rs[(wc ? 1 : 0) * 128 + wr + (lane >> 4) * 4 + mi * 16 + r] = psum[mi][r];
    }
    __syncthreads();
    if (t < 128)
        rspart[((long long)blockIdx.z * 4 + blockIdx.x) * 128 + t] = rs[t] + rs[128 + t];
}

// ---------------- u GEMM: A = E (gload dbuf); B = f32 T natural reg-staged ----------------
__global__ void __launch_bounds__(256, 2)
gemm_u_scaled(const bf16* __restrict__ A /*E*/, const float* __restrict__ Tg,
              bf16* __restrict__ C, const float* __restrict__ rspart) {
    __shared__ char smem[49152];
    bf16* AsB = (bf16*)smem;
    bf16* Bs  = (bf16*)(smem + 32768);
    A  += (long long)blockIdx.z * ((long long)Nn * Ll);
    Tg += (long long)blockIdx.z * ((long long)Cc * Ll);
    C  += (long long)blockIdx.z * ((long long)Nn * Cc);
    const float* rp = rspart + (long long)blockIdx.z * 512;
    const int n0 = blockIdx.x * 128;
    const int t = threadIdx.x, lane = t & 63, w = t >> 6;
    const int wr = (w >> 1) * 64, wc = (w & 1) * 64;
    const int lr = lane & 15, hi4 = (lane >> 4) * 16, sw = (lr & 7) << 4;
    const bf16* gA[4]; int lo[4];
    #pragma unroll
    for (int p = 0; p < 4; ++p) {
        int o = w * 1024 + lane * 16 + p * 4096;
        int row = o >> 7;
        int scol = ((o & 127) ^ ((row & 7) << 4)) >> 1;
        lo[p] = o;
        gA[p] = A + (long long)row * Ll + scol;
    }
    const int s_c = t >> 1, s_half = (t & 1) * 32;
    float4 treg[8];
    #pragma unroll
    for (int p = 0; p < 4; ++p) gload_lds16(gA[p], (char*)AsB + lo[p]);
    #pragma unroll
    for (int i = 0; i < 8; ++i)
        treg[i] = *(const float4*)(Tg + (long long)(n0 + s_c) * Ll + s_half + i * 4);
    f32x4 acc[4][4] = {};
    int cur = 0;
    const int NT = Ll / 64;
    for (int kt = 0; kt < NT; ++kt) {
        if (kt + 1 < NT) {
            #pragma unroll
            for (int p = 0; p < 4; ++p)
                gload_lds16(gA[p] + (kt + 1) * 64, (char*)AsB + (cur ^ 1) * 16384 + lo[p]);
        }
        __syncthreads();
        #pragma unroll
        for (int q = 0; q < 4; ++q) {
            bf16x8 bv;
            #pragma unroll
            for (int j = 0; j < 4; ++j) {
                bv[j]     = (bf16)((const float*)&treg[q * 2])[j];
                bv[4 + j] = (bf16)((const float*)&treg[q * 2 + 1])[j];
            }
            *(bf16x8*)((char*)Bs + ((s_c * 128 + (s_half + q * 8) * 2) ^ ((s_c & 7) << 4))) = bv;
        }
        if (kt + 1 < NT) {
            #pragma unroll
            for (int i = 0; i < 8; ++i)
                treg[i] = *(const float4*)(Tg + (long long)(n0 + s_c) * Ll
                                           + (kt + 1) * 64 + s_half + i * 4);
        }
        __syncthreads();
        const bf16* As_ = AsB + cur * 8192;
        #pragma unroll
        for (int kk = 0; kk < 2; ++kk) {
            bf16x8 af[4], bfr[4];
            #pragma unroll
            for (int i = 0; i < 4; ++i) {
                int ra = wr + i * 16 + lr;
                int rb = wc + i * 16 + lr;
                af[i]  = *(const bf16x8*)((const char*)As_ + (((ra << 7) + (kk << 6) + hi4) ^ sw));
                bfr[i] = *(const bf16x8*)((const char*)Bs  + (((rb << 7) + (kk << 6) + hi4) ^ sw));
            }
            #pragma unroll
            for (int mi = 0; mi < 4; ++mi)
                #pragma unroll
                for (int ni = 0; ni < 4; ++ni)
                    acc[mi][ni] = __builtin_amdgcn_mfma_f32_16x16x32_bf16(
                        af[mi], bfr[ni], acc[mi][ni], 0, 0, 0);
        }
        cur ^= 1;
    }
    const int rbase = wr + (lane >> 4) * 4;
    const int cbase = n0 + wc + lr;
    #pragma unroll
    for (int mi = 0; mi < 4; ++mi)
        #pragma unroll
        for (int r = 0; r < 4; ++r) {
            int row = rbase + mi * 16 + r;
            float inv = 1.f / (rp[row] + rp[128 + row] + rp[256 + row] + rp[384 + row]);
            #pragma unroll
            for (int ni = 0; ni < 4; ++ni)
                C[(long long)row * Cc + (cbase + ni * 16)] = (bf16)(acc[mi][ni][r] * inv);
        }
}

// ctx GEMM + LN1 residual/stats epilogue (Z1 bf16):
__global__ void __launch_bounds__(256, 2)
gemm_ctx_ln1(const bf16* __restrict__ A /*Wv*/, const bf16* __restrict__ Bt /*u*/,
             const float* __restrict__ X, bf16* __restrict__ Z1, float* __restrict__ partials,
             int K, long long sBt) {
    const int N = Nn;
    Bt += (long long)blockIdx.z * sBt;
    X  += (long long)blockIdx.z * PLANE;
    Z1 += (long long)blockIdx.z * PLANE;
    GEMM_PROLOGUE_AND_LOOP(A, Bt, K, K, 0, 0)
    const int rbase = m0 + wr + (lane >> 4) * 4;
    const int cbase = n0 + wc + lr;
    float s = 0.f, ss = 0.f;
    #pragma unroll
    for (int mi = 0; mi < 4; ++mi)
        #pragma unroll
        for (int ni = 0; ni < 4; ++ni)
            #pragma unroll
            for (int r = 0; r < 4; ++r) {
                long long idx = (long long)(rbase + mi * 16 + r) * N + (cbase + ni * 16);
                float zv = acc[mi][ni][r] + X[idx];
                Z1[idx] = (bf16)zv;
                s += zv; ss += zv * zv;
            }
    #pragma unroll
    for (int off = 32; off; off >>= 1) { s += __shfl_xor(s, off); ss += __shfl_xor(ss, off); }
    __shared__ float red[8];
    if (lane == 0) { red[w] = s; red[4 + w] = ss; }
    __syncthreads();
    if (t == 0) {
        float S = red[0] + red[1] + red[2] + red[3];
        float SS = red[4] + red[5] + red[6] + red[7];
        float* p = partials + ((long long)blockIdx.z * 8 + blockIdx.y) * 2;
        p[0] = S; p[1] = SS;
    }
}

// FFN GEMM + LN2 epilogue (Xout recomputed from bf16 Z1 + pp1; Z2 bf16):
__global__ void __launch_bounds__(256, 2)
gemm_ffn_ln2(const bf16* __restrict__ A /*hT*/, const bf16* __restrict__ Bt /*Wf2*/,
             const bf16* __restrict__ Z1, const float* __restrict__ pp1,
             const float* __restrict__ gamma, const float* __restrict__ beta,
             bf16* __restrict__ Z2, float* __restrict__ partials,
             int K, long long sA) {
    A  += (long long)blockIdx.z * sA;
    Z1 += (long long)blockIdx.z * PLANE;
    Z2 += (long long)blockIdx.z * PLANE;
    float S1 = 0.f, SS1 = 0.f;
    #pragma unroll
    for (int j = 0; j < 8; ++j) {
        S1  += pp1[((long long)blockIdx.z * 8 + j) * 2];
        SS1 += pp1[((long long)blockIdx.z * 8 + j) * 2 + 1];
    }
    const float mean1 = S1 * INV_PLANE;
    const float rstd1 = rsqrtf(SS1 * INV_PLANE - mean1 * mean1 + 1e-5f);
    GEMM_PROLOGUE_AND_LOOP(A, Bt, K, K, 0, 0)
    const int rbase = m0 + wr + (lane >> 4) * 4;
    const int cbase = n0 + wc + lr;
    float s = 0.f, ss = 0.f;
    #pragma unroll
    for (int mi = 0; mi < 4; ++mi)
        #pragma unroll
        for (int ni = 0; ni < 4; ++ni) {
            long long a = (long long)(cbase + ni * 16) * Nn + rbase + mi * 16;
            bf16x4 z1v = *(const bf16x4*)(Z1 + a);
            float4 g  = *(const float4*)(gamma + a);
            float4 be = *(const float4*)(beta + a);
            float x0 = ((float)z1v[0] - mean1) * rstd1 * g.x + be.x;
            float x1 = ((float)z1v[1] - mean1) * rstd1 * g.y + be.y;
            float x2 = ((float)z1v[2] - mean1) * rstd1 * g.z + be.z;
            float x3 = ((float)z1v[3] - mean1) * rstd1 * g.w + be.w;
            float z0 = acc[mi][ni][0] + x0, z1 = acc[mi][ni][1] + x1;
            float z2 = acc[mi][ni][2] + x2, z3 = acc[mi][ni][3] + x3;
            bf16x4 zo = { (bf16)z0, (bf16)z1, (bf16)z2, (bf16)z3 };
            *(bf16x4*)(Z2 + a) = zo;
            s  += z0 + z1 + z2 + z3;
            ss += z0 * z0 + z1 * z1 + z2 * z2 + z3 * z3;
        }
    #pragma unroll
    for (int off = 32; off; off >>= 1) { s += __shfl_xor(s, off); ss += __shfl_xor(ss, off); }
    __shared__ float red[8];
    if (lane == 0) { red[w] = s; red[4 + w] = ss; }
    __syncthreads();
    if (t == 0) {
        float S = red[0] + red[1] + red[2] + red[3];
        float SS = red[4] + red[5] + red[6] + red[7];
        float* p = partials + ((long long)blockIdx.z * 8 + blockIdx.x) * 2;
        p[0] = S; p[1] = SS;
    }
}

// ---------------- LN1 normalize + tiled transposed bf16 output ----------------
__global__ void ln1_norm_transpose(const bf16* __restrict__ Z1, const float* __restrict__ partials,
                                   const float* __restrict__ gamma, const float* __restrict__ beta,
                                   bf16* __restrict__ XoutT) {
    int b = blockIdx.z;
    float S = 0.f, SS = 0.f;
    #pragma unroll
    for (int j = 0; j < 8; ++j) {
        S  += partials[((long long)b * 8 + j) * 2];
        SS += partials[((long long)b * 8 + j) * 2 + 1];
    }
    float mean = S * INV_PLANE;
    float rstd = rsqrtf(SS * INV_PLANE - mean * mean + 1e-5f);
    __shared__ float tile[64][65];
    long long base = (long long)b * PLANE;
    int n0 = blockIdx.x * 64, c0 = blockIdx.y * 64;
    int t = threadIdx.x;
    int rl = t >> 4, sc = (t & 15) * 4;
    #pragma unroll
    for (int p = 0; p < 4; ++p) {
        int r = p * 16 + rl;
        long long idx = (long long)(c0 + r) * Nn + n0 + sc;
        bf16x4 z  = *(const bf16x4*)(Z1 + base + idx);
        float4 g  = *(const float4*)(gamma + idx);
        float4 be = *(const float4*)(beta + idx);
        float4 o = {((float)z[0] - mean) * rstd * g.x + be.x,
                    ((float)z[1] - mean) * rstd * g.y + be.y,
                    ((float)z[2] - mean) * rstd * g.z + be.z,
                    ((float)z[3] - mean) * rstd * g.w + be.w};
        *(float4*)&tile[r][sc] = o;
    }
    __syncthreads();
    long long tb = ((long long)(n0 >> 6) * (Cc >> 6) + (c0 >> 6)) * 4096;
    int sb = t >> 3, rg = (t & 7) * 8;
    #pragma unroll
    for (int p = 0; p < 2; ++p) {
        int n = sb + p * 32;
        bf16x8 o;
        #pragma unroll
        for (int j = 0; j < 8; ++j) o[j] = (bf16)tile[rg + j][n];
        *(bf16x8*)(XoutT + base + tb + n * 64 + rg) = o;
    }
}

// ---------------- final LN ----------------
__global__ void ln2_final(const bf16* __restrict__ Z2, const float* __restrict__ partials,
                          const float* __restrict__ gamma, const float* __restrict__ beta,
                          float* __restrict__ out) {
    int b = blockIdx.y;
    float S = 0.f, SS = 0.f;
    #pragma unroll
    for (int j = 0; j < 8; ++j) {
        S  += partials[((long long)b * 8 + j) * 2];
        SS += partials[((long long)b * 8 + j) * 2 + 1];
    }
    float mean = S * INV_PLANE;
    float rstd = rsqrtf(SS * INV_PLANE - mean * mean + 1e-5f);
    long long base = (long long)b * PLANE;
    int i = (blockIdx.x * 256 + threadIdx.x) * 8;
    bf16x8 z = *(const bf16x8*)(Z2 + base + i);
    #pragma unroll
    for (int h = 0; h < 2; ++h) {
        float4 g  = *(const float4*)(gamma + i + h * 4);
        float4 be = *(const float4*)(beta + i + h * 4);
        float4 o = {((float)z[h * 4 + 0] - mean) * rstd * g.x + be.x,
                    ((float)z[h * 4 + 1] - mean) * rstd * g.y + be.y,
                    ((float)z[h * 4 + 2] - mean) * rstd * g.z + be.z,
                    ((float)z[h * 4 + 3] - mean) * rstd * g.w + be.w};
        *(float4*)(out + base + i + h * 4) = o;
    }
}

extern "C" void kernel_launch(void* const* d_in, const int* in_sizes, int n_in,
                              void* d_out, int out_size, void* d_ws, size_t ws_size,
                              hipStream_t stream) {
    const float* X   = (const float*)d_in[0];
    const float* T   = (const float*)d_in[1];
    const float* Wq  = (const float*)d_in[2];
    const float* Wk  = (const float*)d_in[3];
    const float* Wv  = (const float*)d_in[4];
    const float* Wf1 = (const float*)d_in[5];
    const float* Wf2 = (const float*)d_in[6];
    const float* gamma = (const float*)d_in[7];
    const float* beta  = (const float*)d_in[8];
    float* out = (float*)d_out;
    char* ws = (char*)d_ws;
    const size_t MB = 1ull << 20;

    bf16* WvB  = (bf16*)(ws + 0 * MB);
    bf16* Wf1B = (bf16*)(ws + 2 * MB);
    bf16* Wf2B = (bf16*)(ws + 4 * MB);
    bf16* WqT  = (bf16*)(ws + 6 * MB);
    bf16* WkT  = (bf16*)(ws + 8 * MB);
    bf16* G2   = (bf16*)(ws + 10 * MB);
    bf16* Xt   = (bf16*)(ws + 12 * MB);
    bf16* Z1   = (bf16*)(ws + 28 * MB);
    bf16* XoutT= (bf16*)(ws + 44 * MB);
    bf16* hT   = (bf16*)(ws + 60 * MB);
    bf16* e    = (bf16*)(ws + 76 * MB);
    bf16* Z2   = (bf16*)(ws + 92 * MB);
    bf16* E    = (bf16*)(ws + 108 * MB);
    bf16* u    = (bf16*)(ws + 116 * MB);
    float* G2p = (float*)(ws + 132 * MB);
    float* pp1 = (float*)(ws + 148 * MB);
    float* pp2 = (float*)(ws + 148 * MB + 65536);
    float* rsp = (float*)(ws + 149 * MB);

    dim3 blk256(256);

    prep_all<<<dim3(5632), blk256, 0, stream>>>(
        Wv, Wf1, Wf2, Wq, Wk, X, WvB, Wf1B, Wf2B, WqT, WkT, Xt);

    gemm_tn<float, false, 1, 1><<<dim3(8, 8, 4), blk256, 0, stream>>>(
        WkT, WqT, G2p, Cc, Cc, 256, Cc, 16384, 16384, 1048576, 1.f);
    g2_reduce<<<dim3(1024), blk256, 0, stream>>>(G2p, G2);

    gemm_tn<bf16, false, 1, 0><<<dim3(8, 1, Bb), blk256, 0, stream>>>(
        Xt, G2, e, Nn, Cc, Cc, Cc, (long long)Nn * Cc, 0, (long long)Nn * Cc, 1.f);
    gemm_sim_exp<<<dim3(4, 1, Bb), blk256, 0, stream>>>(e, T, E, rsp);
    gemm_u_scaled<<<dim3(8, 1, Bb), blk256, 0, stream>>>(E, T, u, rsp);
    gemm_ctx_ln1<<<dim3(1, 8, Bb), blk256, 0, stream>>>(
        WvB, u, X, Z1, pp1, Cc, (long long)Nn * Cc);
    ln1_norm_transpose<<<dim3(Nn / 64, Cc / 64, Bb), blk256, 0, stream>>>(
        Z1, pp1, gamma, beta, XoutT);
    gemm_tn<bf16, true, 1, 0><<<dim3(8, 1, Bb), blk256, 0, stream>>>(
        XoutT, Wf1B, hT, Nn, Cc, Cc, Cc, (long long)Nn * Cc, 0, (long long)Nn * Cc, 1.f);
    gemm_ffn_ln2<<<dim3(8, 1, Bb), blk256, 0, stream>>>(
        hT, Wf2B, Z1, pp1, gamma, beta, Z2, pp2, Cc, (long long)Nn * Cc);
    ln2_final<<<dim3(64, Bb), blk256, 0, stream>>>(Z2, pp2, gamma, beta, out);
}

// Round 10
// 259.655 us; speedup vs baseline: 1.1294x; 1.0774x over previous
//
#include <hip/hip_runtime.h>

// Transformer decoder block, MI355X gfx950. Round 10: sim retiled to 128x64
// (grid 512, 2/CU, LDS 33KB) and u retiled to 128x64 c-tiles (grid 1024,
// 4/CU, LDS 40KB) — fixes the 1-block/CU latency chain found in round 9.
// All other kernels unchanged from round 9.

using bf16   = __bf16;
using bf16x4 = __attribute__((ext_vector_type(4))) __bf16;
using bf16x8 = __attribute__((ext_vector_type(8))) __bf16;
using f32x4  = __attribute__((ext_vector_type(4))) float;

static constexpr int  Bb = 64;
static constexpr int  Cc = 1024;
static constexpr int  Nn = 128;
static constexpr int  Ll = 512;
static constexpr long long PLANE = (long long)Cc * Nn;
static constexpr float INV_PLANE = 1.0f / 131072.0f;

__device__ __forceinline__ void gload_lds16(const void* g, void* l) {
    __builtin_amdgcn_global_load_lds(
        (__attribute__((address_space(1))) void*)g,
        (__attribute__((address_space(3))) void*)l,
        16, 0, 0);
}

// ---------------- prep: weight casts + Wq/Wk transposes + Xt (tiled) ----------------
__global__ void __launch_bounds__(256)
prep_all(const float* __restrict__ Wv, const float* __restrict__ Wf1,
         const float* __restrict__ Wf2, const float* __restrict__ Wq,
         const float* __restrict__ Wk, const float* __restrict__ X,
         bf16* __restrict__ WvB, bf16* __restrict__ Wf1B, bf16* __restrict__ Wf2B,
         bf16* __restrict__ WqT, bf16* __restrict__ WkT, bf16* __restrict__ Xt) {
    __shared__ float tile[64][65];
    const int bx = blockIdx.x;
    const int t  = threadIdx.x;
    if (bx < 3072) {
        const float* in = bx < 1024 ? Wv : (bx < 2048 ? Wf1 : Wf2);
        bf16* out       = bx < 1024 ? WvB : (bx < 2048 ? Wf1B : Wf2B);
        int i = (bx & 1023) * 256 + t;
        float4 v = reinterpret_cast<const float4*>(in)[i];
        bf16x4 o = { (bf16)v.x, (bf16)v.y, (bf16)v.z, (bf16)v.w };
        reinterpret_cast<bf16x4*>(out)[i] = o;
        return;
    }
    const float* in; bf16* outT;
    int R, S, bxx, byy, bz = 0;
    if (bx < 3584) {
        int j = bx - 3072;
        in = (j >= 256) ? Wk : Wq; outT = (j >= 256) ? WkT : WqT;
        R = Cc; S = Cc; j &= 255; bxx = j & 15; byy = j >> 4;
    } else {
        int j = bx - 3584; bz = j >> 5; j &= 31;
        bxx = j & 1; byy = j >> 1; in = X; outT = Xt; R = Cc; S = Nn;
    }
    long long plane = (long long)R * S;
    in   += (long long)bz * plane;
    outT += (long long)bz * plane;
    int s0 = bxx * 64, r0 = byy * 64;
    int rl = t >> 4, sc = (t & 15) * 4;
    #pragma unroll
    for (int p = 0; p < 4; ++p) {
        int r = p * 16 + rl;
        float4 v = *(const float4*)(in + (long long)(r0 + r) * S + s0 + sc);
        *(float4*)&tile[r][sc] = v;
    }
    __syncthreads();
    long long tb = ((long long)(s0 >> 6) * (R >> 6) + (r0 >> 6)) * 4096;
    int sb = t >> 3, rg = (t & 7) * 8;
    #pragma unroll
    for (int p = 0; p < 2; ++p) {
        int s = sb + p * 32;
        bf16x8 o;
        #pragma unroll
        for (int j = 0; j < 8; ++j) o[j] = (bf16)tile[rg + j][s];
        *(bf16x8*)(outT + tb + s * 64 + rg) = o;
    }
}

// ---------------- generic TN GEMM core (gload-staged both sides) ----------------
#define GEMM_PROLOGUE_AND_LOOP(A_, Bt_, KLOOP_, LD_, TA_, TB_)                     \
    __shared__ bf16 As[2][128 * 64];                                               \
    __shared__ bf16 Bs[2][128 * 64];                                               \
    const int n0   = blockIdx.x * 128;                                             \
    const int m0   = blockIdx.y * 128;                                             \
    const int t    = threadIdx.x;                                                  \
    const int lane = t & 63;                                                       \
    const int w    = t >> 6;                                                       \
    const int wr   = (w >> 1) * 64;                                                \
    const int wc   = (w & 1) * 64;                                                 \
    const int lr   = lane & 15;                                                    \
    const int hi4  = (lane >> 4) * 16;                                             \
    const int sw   = (lr & 7) << 4;                                                \
    const int stepA_ = (TA_) ? 4096 : 64;                                          \
    const int stepB_ = (TB_) ? 4096 : 64;                                          \
    const bf16* gA[4]; const bf16* gB[4]; int lo[4];                               \
    _Pragma("unroll")                                                              \
    for (int p = 0; p < 4; ++p) {                                                  \
        int o = w * 1024 + lane * 16 + p * 4096;                                   \
        int row = o >> 7;                                                          \
        int scol = ((o & 127) ^ ((row & 7) << 4)) >> 1;                            \
        lo[p] = o;                                                                 \
        int ra = m0 + row, rb = n0 + row;                                          \
        gA[p] = (TA_) ? A_ + ((long long)(ra >> 6) * (LD_ >> 6)) * 4096            \
                           + (ra & 63) * 64 + scol                                 \
                      : A_ + (long long)ra * LD_ + scol;                           \
        gB[p] = (TB_) ? Bt_ + ((long long)(rb >> 6) * (LD_ >> 6)) * 4096           \
                            + (rb & 63) * 64 + scol                                \
                      : Bt_ + (long long)rb * LD_ + scol;                          \
    }                                                                              \
    f32x4 acc[4][4] = {};                                                          \
    const int NT_ = KLOOP_ / 64;                                                   \
    _Pragma("unroll")                                                              \
    for (int p = 0; p < 4; ++p) gload_lds16(gA[p], (char*)As[0] + lo[p]);          \
    _Pragma("unroll")                                                              \
    for (int p = 0; p < 4; ++p) gload_lds16(gB[p], (char*)Bs[0] + lo[p]);          \
    __syncthreads();                                                               \
    int cur_ = 0;                                                                  \
    for (int kt = 0; kt < NT_; ++kt) {                                             \
        if (kt + 1 < NT_) {                                                        \
            _Pragma("unroll")                                                      \
            for (int p = 0; p < 4; ++p)                                            \
                gload_lds16(gA[p] + (long long)(kt + 1) * stepA_,                  \
                            (char*)As[cur_ ^ 1] + lo[p]);                          \
            _Pragma("unroll")                                                      \
            for (int p = 0; p < 4; ++p)                                            \
                gload_lds16(gB[p] + (long long)(kt + 1) * stepB_,                  \
                            (char*)Bs[cur_ ^ 1] + lo[p]);                          \
        }                                                                          \
        const bf16* As_ = As[cur_]; const bf16* Bs_ = Bs[cur_];                    \
        _Pragma("unroll")                                                          \
        for (int kk = 0; kk < 2; ++kk) {                                           \
            bf16x8 af[4], bfr[4];                                                  \
            _Pragma("unroll")                                                      \
            for (int i = 0; i < 4; ++i) {                                          \
                int ra = wr + i * 16 + lr;                                         \
                int rb = wc + i * 16 + lr;                                         \
                af[i]  = *(const bf16x8*)((const char*)As_ +                       \
                          ((((ra << 7) + (kk << 6) + hi4)) ^ sw));                 \
                bfr[i] = *(const bf16x8*)((const char*)Bs_ +                       \
                          ((((rb << 7) + (kk << 6) + hi4)) ^ sw));                 \
            }                                                                      \
            _Pragma("unroll")                                                      \
            for (int mi = 0; mi < 4; ++mi)                                         \
                _Pragma("unroll")                                                  \
                for (int ni = 0; ni < 4; ++ni)                                     \
                    acc[mi][ni] = __builtin_amdgcn_mfma_f32_16x16x32_bf16(         \
                        af[mi], bfr[ni], acc[mi][ni], 0, 0, 0);                    \
        }                                                                          \
        __syncthreads();                                                           \
        cur_ ^= 1;                                                                 \
    }

template <typename OutT, bool RELU, int TA, int TB>
__global__ void __launch_bounds__(256, 2)
gemm_tn(const bf16* __restrict__ A, const bf16* __restrict__ Bt, OutT* __restrict__ C,
        int M, int N, int KLOOP, int ld, long long sA, long long sBt, long long sC,
        float scale) {
    A  += (long long)blockIdx.z * sA;
    Bt += (long long)blockIdx.z * sBt;
    C  += (long long)blockIdx.z * sC;
    GEMM_PROLOGUE_AND_LOOP(A, Bt, KLOOP, ld, TA, TB)
    const int rbase = m0 + wr + (lane >> 4) * 4;
    const int cbase = n0 + wc + lr;
    #pragma unroll
    for (int mi = 0; mi < 4; ++mi)
        #pragma unroll
        for (int ni = 0; ni < 4; ++ni)
            #pragma unroll
            for (int r = 0; r < 4; ++r) {
                float v = acc[mi][ni][r] * scale;
                if (RELU) v = fmaxf(v, 0.0f);
                C[(long long)(rbase + mi * 16 + r) * N + (cbase + ni * 16)] = (OutT)v;
            }
}

__global__ void g2_reduce(const float* __restrict__ p, bf16* __restrict__ g2) {
    int i = (blockIdx.x * 256 + threadIdx.x) * 4;
    float4 a = *(const float4*)(p + i);
    float4 b = *(const float4*)(p + 1048576 + i);
    float4 c = *(const float4*)(p + 2097152 + i);
    float4 d = *(const float4*)(p + 3145728 + i);
    bf16x4 o = { (bf16)(a.x + b.x + c.x + d.x), (bf16)(a.y + b.y + c.y + d.y),
                 (bf16)(a.z + b.z + c.z + d.z), (bf16)(a.w + b.w + c.w + d.w) };
    *(bf16x4*)(g2 + i) = o;
}

// ---------------- sim GEMM v3: 128(n) x 64(l) tile, grid (8,1,B) = 512 blocks ----------------
// Wave layout 4Mx1N: wave w = rows [w*32, w*32+32), all 64 l-cols. acc[2][4].
// A = e (single-buf gload As 16K); B = f32 T chunk -> bf16 scr [64][66] -> swizzled Bs 8K.
// E[n,l] = exp(acc/32); per-tile rowsums written direct to rspart[(b*8+bx)*128+n].
__global__ void __launch_bounds__(256, 2)
gemm_sim_exp(const bf16* __restrict__ A /*e*/, const float* __restrict__ Tg,
             bf16* __restrict__ E, float* __restrict__ rspart) {
    __shared__ char smem[33024];               // As 16384 + Bs 8192 + scr 8448
    bf16* Asb = (bf16*)smem;
    bf16* Bs  = (bf16*)(smem + 16384);
    bf16* scr = (bf16*)(smem + 24576);         // [64][66] bf16
    A  += (long long)blockIdx.z * ((long long)Nn * Cc);
    Tg += (long long)blockIdx.z * ((long long)Cc * Ll);
    E  += (long long)blockIdx.z * ((long long)Nn * Ll);
    const int l0 = blockIdx.x * 64;
    const int t = threadIdx.x, lane = t & 63, w = t >> 6;
    const int lr = lane & 15, hi4 = (lane >> 4) * 16, sw = (lr & 7) << 4;
    const bf16* gA[4]; int lo[4];
    #pragma unroll
    for (int p = 0; p < 4; ++p) {
        int o = w * 1024 + lane * 16 + p * 4096;
        int row = o >> 7;
        int scol = ((o & 127) ^ ((row & 7) << 4)) >> 1;
        lo[p] = o;
        gA[p] = A + (long long)row * Cc + scol;
    }
    const int s_c = t >> 2, s_l = (t & 3) * 16;      // T stage: c-row, l-base (16 floats)
    float4 treg[4];
    #pragma unroll
    for (int i = 0; i < 4; ++i)
        treg[i] = *(const float4*)(Tg + (long long)s_c * Ll + l0 + s_l + i * 4);
    f32x4 acc[2][4] = {};
    const int NT = Cc / 64;
    for (int kt = 0; kt < NT; ++kt) {
        // scr[c][l] write (bf16, pad 66)
        #pragma unroll
        for (int i = 0; i < 4; ++i) {
            float4 v = treg[i];
            bf16x4 o = { (bf16)v.x, (bf16)v.y, (bf16)v.z, (bf16)v.w };
            *(bf16x4*)(scr + s_c * 66 + s_l + i * 4) = o;
        }
        __syncthreads();   // B1: scr visible; prior MFMA reads of As/Bs done
        #pragma unroll
        for (int p = 0; p < 4; ++p) gload_lds16(gA[p] + kt * 64, (char*)Asb + lo[p]);
        // Bs build: row = l (t&63), col-octets (t>>6)*16 + p*8
        {
            int lrow = t & 63;
            #pragma unroll
            for (int p = 0; p < 2; ++p) {
                int c8 = (t >> 6) * 16 + p * 8;
                bf16x8 bv;
                #pragma unroll
                for (int j = 0; j < 8; ++j) bv[j] = scr[(c8 + j) * 66 + lrow];
                *(bf16x8*)((char*)Bs + (((lrow << 7) + c8 * 2) ^ ((lrow & 7) << 4))) = bv;
            }
        }
        if (kt + 1 < NT) {
            #pragma unroll
            for (int i = 0; i < 4; ++i)
                treg[i] = *(const float4*)(Tg + (long long)((kt + 1) * 64 + s_c) * Ll
                                           + l0 + s_l + i * 4);
        }
        __syncthreads();   // B2: Bs visible + As gloads drained
        #pragma unroll
        for (int kk = 0; kk < 2; ++kk) {
            bf16x8 af[2], bfr[4];
            #pragma unroll
            for (int mi = 0; mi < 2; ++mi) {
                int ra = w * 32 + mi * 16 + lr;
                af[mi] = *(const bf16x8*)((const char*)Asb + (((ra << 7) + (kk << 6) + hi4) ^ sw));
            }
            #pragma unroll
            for (int ni = 0; ni < 4; ++ni) {
                int rb = ni * 16 + lr;
                bfr[ni] = *(const bf16x8*)((const char*)Bs + (((rb << 7) + (kk << 6) + hi4) ^ sw));
            }
            #pragma unroll
            for (int mi = 0; mi < 2; ++mi)
                #pragma unroll
                for (int ni = 0; ni < 4; ++ni)
                    acc[mi][ni] = __builtin_amdgcn_mfma_f32_16x16x32_bf16(
                        af[mi], bfr[ni], acc[mi][ni], 0, 0, 0);
        }
    }
    // epilogue: exp, store E, per-row sums (row owned by exactly one wave)
    float psum[2][4];
    #pragma unroll
    for (int mi = 0; mi < 2; ++mi)
        #pragma unroll
        for (int r = 0; r < 4; ++r) psum[mi][r] = 0.f;
    #pragma unroll
    for (int mi = 0; mi < 2; ++mi)
        #pragma unroll
        for (int ni = 0; ni < 4; ++ni)
            #pragma unroll
            for (int r = 0; r < 4; ++r) {
                int row = w * 32 + mi * 16 + (lane >> 4) * 4 + r;
                float ev = __expf(acc[mi][ni][r] * 0.03125f);
                E[(long long)row * Ll + l0 + ni * 16 + lr] = (bf16)ev;
                psum[mi][r] += ev;
            }
    #pragma unroll
    for (int mi = 0; mi < 2; ++mi)
        #pragma unroll
        for (int r = 0; r < 4; ++r) {
            float v = psum[mi][r];
            v += __shfl_xor(v, 1); v += __shfl_xor(v, 2);
            v += __shfl_xor(v, 4); v += __shfl_xor(v, 8);
            psum[mi][r] = v;
        }
    if (lr == 0) {
        float* rp = rspart + ((long long)blockIdx.z * 8 + blockIdx.x) * 128;
        #pragma unroll
        for (int mi = 0; mi < 2; ++mi)
            #pragma unroll
            for (int r = 0; r < 4; ++r)
                rp[w * 32 + mi * 16 + (lane >> 4) * 4 + r] = psum[mi][r];
    }
}

// ---------------- u GEMM v2: 128(n) x 64(c) tile, grid (16,1,B) = 1024 blocks ----------------
// Wave layout 4Mx1N. A = E (dbuf gload As 2x16K); B = f32 T natural rows (c) reg-staged -> Bs 8K.
// u[n,c] = acc / rowsum[n], rowsum = sum of 8 rspart tiles.
__global__ void __launch_bounds__(256, 4)
gemm_u_scaled(const bf16* __restrict__ A /*E*/, const float* __restrict__ Tg,
              bf16* __restrict__ C, const float* __restrict__ rspart) {
    __shared__ char smem[40960];               // As dbuf 32768 + Bs 8192
    bf16* AsB = (bf16*)smem;
    bf16* Bs  = (bf16*)(smem + 32768);
    A  += (long long)blockIdx.z * ((long long)Nn * Ll);
    Tg += (long long)blockIdx.z * ((long long)Cc * Ll);
    C  += (long long)blockIdx.z * ((long long)Nn * Cc);
    const float* rp = rspart + (long long)blockIdx.z * 1024;
    const int c0 = blockIdx.x * 64;
    const int t = threadIdx.x, lane = t & 63, w = t >> 6;
    const int lr = lane & 15, hi4 = (lane >> 4) * 16, sw = (lr & 7) << 4;
    const bf16* gA[4]; int lo[4];
    #pragma unroll
    for (int p = 0; p < 4; ++p) {
        int o = w * 1024 + lane * 16 + p * 4096;
        int row = o >> 7;
        int scol = ((o & 127) ^ ((row & 7) << 4)) >> 1;
        lo[p] = o;
        gA[p] = A + (long long)row * Ll + scol;
    }
    const int s_c = t >> 2, s_l = (t & 3) * 16;     // B stage: c-row, l-base
    float4 treg[4];
    #pragma unroll
    for (int p = 0; p < 4; ++p) gload_lds16(gA[p], (char*)AsB + lo[p]);
    #pragma unroll
    for (int i = 0; i < 4; ++i)
        treg[i] = *(const float4*)(Tg + (long long)(c0 + s_c) * Ll + s_l + i * 4);
    f32x4 acc[2][4] = {};
    int cur = 0;
    const int NT = Ll / 64;
    for (int kt = 0; kt < NT; ++kt) {
        if (kt + 1 < NT) {
            #pragma unroll
            for (int p = 0; p < 4; ++p)
                gload_lds16(gA[p] + (kt + 1) * 64, (char*)AsB + (cur ^ 1) * 16384 + lo[p]);
        }
        __syncthreads();   // B1: prior MFMA Bs reads done
        #pragma unroll
        for (int p = 0; p < 2; ++p) {
            bf16x8 bv;
            #pragma unroll
            for (int j = 0; j < 4; ++j) {
                bv[j]     = (bf16)((const float*)&treg[p * 2])[j];
                bv[4 + j] = (bf16)((const float*)&treg[p * 2 + 1])[j];
            }
            *(bf16x8*)((char*)Bs + (((s_c << 7) + (s_l + p * 8) * 2) ^ ((s_c & 7) << 4))) = bv;
        }
        if (kt + 1 < NT) {
            #pragma unroll
            for (int i = 0; i < 4; ++i)
                treg[i] = *(const float4*)(Tg + (long long)(c0 + s_c) * Ll
                                           + (kt + 1) * 64 + s_l + i * 4);
        }
        __syncthreads();   // B2: Bs visible + gloads drained
        const bf16* As_ = AsB + cur * 8192;
        #pragma unroll
        for (int kk = 0; kk < 2; ++kk) {
            bf16x8 af[2], bfr[4];
            #pragma unroll
            for (int mi = 0; mi < 2; ++mi) {
                int ra = w * 32 + mi * 16 + lr;
                af[mi] = *(const bf16x8*)((const char*)As_ + (((ra << 7) + (kk << 6) + hi4) ^ sw));
            }
            #pragma unroll
            for (int ni = 0; ni < 4; ++ni) {
                int rb = ni * 16 + lr;
                bfr[ni] = *(const bf16x8*)((const char*)Bs + (((rb << 7) + (kk << 6) + hi4) ^ sw));
            }
            #pragma unroll
            for (int mi = 0; mi < 2; ++mi)
                #pragma unroll
                for (int ni = 0; ni < 4; ++ni)
                    acc[mi][ni] = __builtin_amdgcn_mfma_f32_16x16x32_bf16(
                        af[mi], bfr[ni], acc[mi][ni], 0, 0, 0);
        }
        cur ^= 1;
    }
    #pragma unroll
    for (int mi = 0; mi < 2; ++mi)
        #pragma unroll
        for (int r = 0; r < 4; ++r) {
            int row = w * 32 + mi * 16 + (lane >> 4) * 4 + r;
            float s = 0.f;
            #pragma unroll
            for (int j = 0; j < 8; ++j) s += rp[j * 128 + row];
            float inv = 1.f / s;
            #pragma unroll
            for (int ni = 0; ni < 4; ++ni)
                C[(long long)row * Cc + (c0 + ni * 16 + lr)] = (bf16)(acc[mi][ni][r] * inv);
        }
}

// ctx GEMM + LN1 residual/stats epilogue (Z1 bf16):
__global__ void __launch_bounds__(256, 2)
gemm_ctx_ln1(const bf16* __restrict__ A /*Wv*/, const bf16* __restrict__ Bt /*u*/,
             const float* __restrict__ X, bf16* __restrict__ Z1, float* __restrict__ partials,
             int K, long long sBt) {
    const int N = Nn;
    Bt += (long long)blockIdx.z * sBt;
    X  += (long long)blockIdx.z * PLANE;
    Z1 += (long long)blockIdx.z * PLANE;
    GEMM_PROLOGUE_AND_LOOP(A, Bt, K, K, 0, 0)
    const int rbase = m0 + wr + (lane >> 4) * 4;
    const int cbase = n0 + wc + lr;
    float s = 0.f, ss = 0.f;
    #pragma unroll
    for (int mi = 0; mi < 4; ++mi)
        #pragma unroll
        for (int ni = 0; ni < 4; ++ni)
            #pragma unroll
            for (int r = 0; r < 4; ++r) {
                long long idx = (long long)(rbase + mi * 16 + r) * N + (cbase + ni * 16);
                float zv = acc[mi][ni][r] + X[idx];
                Z1[idx] = (bf16)zv;
                s += zv; ss += zv * zv;
            }
    #pragma unroll
    for (int off = 32; off; off >>= 1) { s += __shfl_xor(s, off); ss += __shfl_xor(ss, off); }
    __shared__ float red[8];
    if (lane == 0) { red[w] = s; red[4 + w] = ss; }
    __syncthreads();
    if (t == 0) {
        float S = red[0] + red[1] + red[2] + red[3];
        float SS = red[4] + red[5] + red[6] + red[7];
        float* p = partials + ((long long)blockIdx.z * 8 + blockIdx.y) * 2;
        p[0] = S; p[1] = SS;
    }
}

// FFN GEMM + LN2 epilogue (Xout recomputed from bf16 Z1 + pp1; Z2 bf16):
__global__ void __launch_bounds__(256, 2)
gemm_ffn_ln2(const bf16* __restrict__ A /*hT*/, const bf16* __restrict__ Bt /*Wf2*/,
             const bf16* __restrict__ Z1, const float* __restrict__ pp1,
             const float* __restrict__ gamma, const float* __restrict__ beta,
             bf16* __restrict__ Z2, float* __restrict__ partials,
             int K, long long sA) {
    A  += (long long)blockIdx.z * sA;
    Z1 += (long long)blockIdx.z * PLANE;
    Z2 += (long long)blockIdx.z * PLANE;
    float S1 = 0.f, SS1 = 0.f;
    #pragma unroll
    for (int j = 0; j < 8; ++j) {
        S1  += pp1[((long long)blockIdx.z * 8 + j) * 2];
        SS1 += pp1[((long long)blockIdx.z * 8 + j) * 2 + 1];
    }
    const float mean1 = S1 * INV_PLANE;
    const float rstd1 = rsqrtf(SS1 * INV_PLANE - mean1 * mean1 + 1e-5f);
    GEMM_PROLOGUE_AND_LOOP(A, Bt, K, K, 0, 0)
    const int rbase = m0 + wr + (lane >> 4) * 4;
    const int cbase = n0 + wc + lr;
    float s = 0.f, ss = 0.f;
    #pragma unroll
    for (int mi = 0; mi < 4; ++mi)
        #pragma unroll
        for (int ni = 0; ni < 4; ++ni) {
            long long a = (long long)(cbase + ni * 16) * Nn + rbase + mi * 16;
            bf16x4 z1v = *(const bf16x4*)(Z1 + a);
            float4 g  = *(const float4*)(gamma + a);
            float4 be = *(const float4*)(beta + a);
            float x0 = ((float)z1v[0] - mean1) * rstd1 * g.x + be.x;
            float x1 = ((float)z1v[1] - mean1) * rstd1 * g.y + be.y;
            float x2 = ((float)z1v[2] - mean1) * rstd1 * g.z + be.z;
            float x3 = ((float)z1v[3] - mean1) * rstd1 * g.w + be.w;
            float z0 = acc[mi][ni][0] + x0, z1 = acc[mi][ni][1] + x1;
            float z2 = acc[mi][ni][2] + x2, z3 = acc[mi][ni][3] + x3;
            bf16x4 zo = { (bf16)z0, (bf16)z1, (bf16)z2, (bf16)z3 };
            *(bf16x4*)(Z2 + a) = zo;
            s  += z0 + z1 + z2 + z3;
            ss += z0 * z0 + z1 * z1 + z2 * z2 + z3 * z3;
        }
    #pragma unroll
    for (int off = 32; off; off >>= 1) { s += __shfl_xor(s, off); ss += __shfl_xor(ss, off); }
    __shared__ float red[8];
    if (lane == 0) { red[w] = s; red[4 + w] = ss; }
    __syncthreads();
    if (t == 0) {
        float S = red[0] + red[1] + red[2] + red[3];
        float SS = red[4] + red[5] + red[6] + red[7];
        float* p = partials + ((long long)blockIdx.z * 8 + blockIdx.x) * 2;
        p[0] = S; p[1] = SS;
    }
}

// ---------------- LN1 normalize + tiled transposed bf16 output ----------------
__global__ void ln1_norm_transpose(const bf16* __restrict__ Z1, const float* __restrict__ partials,
                                   const float* __restrict__ gamma, const float* __restrict__ beta,
                                   bf16* __restrict__ XoutT) {
    int b = blockIdx.z;
    float S = 0.f, SS = 0.f;
    #pragma unroll
    for (int j = 0; j < 8; ++j) {
        S  += partials[((long long)b * 8 + j) * 2];
        SS += partials[((long long)b * 8 + j) * 2 + 1];
    }
    float mean = S * INV_PLANE;
    float rstd = rsqrtf(SS * INV_PLANE - mean * mean + 1e-5f);
    __shared__ float tile[64][65];
    long long base = (long long)b * PLANE;
    int n0 = blockIdx.x * 64, c0 = blockIdx.y * 64;
    int t = threadIdx.x;
    int rl = t >> 4, sc = (t & 15) * 4;
    #pragma unroll
    for (int p = 0; p < 4; ++p) {
        int r = p * 16 + rl;
        long long idx = (long long)(c0 + r) * Nn + n0 + sc;
        bf16x4 z  = *(const bf16x4*)(Z1 + base + idx);
        float4 g  = *(const float4*)(gamma + idx);
        float4 be = *(const float4*)(beta + idx);
        float4 o = {((float)z[0] - mean) * rstd * g.x + be.x,
                    ((float)z[1] - mean) * rstd * g.y + be.y,
                    ((float)z[2] - mean) * rstd * g.z + be.z,
                    ((float)z[3] - mean) * rstd * g.w + be.w};
        *(float4*)&tile[r][sc] = o;
    }
    __syncthreads();
    long long tb = ((long long)(n0 >> 6) * (Cc >> 6) + (c0 >> 6)) * 4096;
    int sb = t >> 3, rg = (t & 7) * 8;
    #pragma unroll
    for (int p = 0; p < 2; ++p) {
        int n = sb + p * 32;
        bf16x8 o;
        #pragma unroll
        for (int j = 0; j < 8; ++j) o[j] = (bf16)tile[rg + j][n];
        *(bf16x8*)(XoutT + base + tb + n * 64 + rg) = o;
    }
}

// ---------------- final LN ----------------
__global__ void ln2_final(const bf16* __restrict__ Z2, const float* __restrict__ partials,
                          const float* __restrict__ gamma, const float* __restrict__ beta,
                          float* __restrict__ out) {
    int b = blockIdx.y;
    float S = 0.f, SS = 0.f;
    #pragma unroll
    for (int j = 0; j < 8; ++j) {
        S  += partials[((long long)b * 8 + j) * 2];
        SS += partials[((long long)b * 8 + j) * 2 + 1];
    }
    float mean = S * INV_PLANE;
    float rstd = rsqrtf(SS * INV_PLANE - mean * mean + 1e-5f);
    long long base = (long long)b * PLANE;
    int i = (blockIdx.x * 256 + threadIdx.x) * 8;
    bf16x8 z = *(const bf16x8*)(Z2 + base + i);
    #pragma unroll
    for (int h = 0; h < 2; ++h) {
        float4 g  = *(const float4*)(gamma + i + h * 4);
        float4 be = *(const float4*)(beta + i + h * 4);
        float4 o = {((float)z[h * 4 + 0] - mean) * rstd * g.x + be.x,
                    ((float)z[h * 4 + 1] - mean) * rstd * g.y + be.y,
                    ((float)z[h * 4 + 2] - mean) * rstd * g.z + be.z,
                    ((float)z[h * 4 + 3] - mean) * rstd * g.w + be.w};
        *(float4*)(out + base + i + h * 4) = o;
    }
}

extern "C" void kernel_launch(void* const* d_in, const int* in_sizes, int n_in,
                              void* d_out, int out_size, void* d_ws, size_t ws_size,
                              hipStream_t stream) {
    const float* X   = (const float*)d_in[0];
    const float* T   = (const float*)d_in[1];
    const float* Wq  = (const float*)d_in[2];
    const float* Wk  = (const float*)d_in[3];
    const float* Wv  = (const float*)d_in[4];
    const float* Wf1 = (const float*)d_in[5];
    const float* Wf2 = (const float*)d_in[6];
    const float* gamma = (const float*)d_in[7];
    const float* beta  = (const float*)d_in[8];
    float* out = (float*)d_out;
    char* ws = (char*)d_ws;
    const size_t MB = 1ull << 20;

    bf16* WvB  = (bf16*)(ws + 0 * MB);
    bf16* Wf1B = (bf16*)(ws + 2 * MB);
    bf16* Wf2B = (bf16*)(ws + 4 * MB);
    bf16* WqT  = (bf16*)(ws + 6 * MB);
    bf16* WkT  = (bf16*)(ws + 8 * MB);
    bf16* G2   = (bf16*)(ws + 10 * MB);
    bf16* Xt   = (bf16*)(ws + 12 * MB);
    bf16* Z1   = (bf16*)(ws + 28 * MB);
    bf16* XoutT= (bf16*)(ws + 44 * MB);
    bf16* hT   = (bf16*)(ws + 60 * MB);
    bf16* e    = (bf16*)(ws + 76 * MB);
    bf16* Z2   = (bf16*)(ws + 92 * MB);
    bf16* E    = (bf16*)(ws + 108 * MB);
    bf16* u    = (bf16*)(ws + 116 * MB);
    float* G2p = (float*)(ws + 132 * MB);
    float* pp1 = (float*)(ws + 148 * MB);
    float* pp2 = (float*)(ws + 148 * MB + 65536);
    float* rsp = (float*)(ws + 149 * MB);    // 64*8*128 f32 = 256 KB

    dim3 blk256(256);

    prep_all<<<dim3(5632), blk256, 0, stream>>>(
        Wv, Wf1, Wf2, Wq, Wk, X, WvB, Wf1B, Wf2B, WqT, WkT, Xt);

    gemm_tn<float, false, 1, 1><<<dim3(8, 8, 4), blk256, 0, stream>>>(
        WkT, WqT, G2p, Cc, Cc, 256, Cc, 16384, 16384, 1048576, 1.f);
    g2_reduce<<<dim3(1024), blk256, 0, stream>>>(G2p, G2);

    gemm_tn<bf16, false, 1, 0><<<dim3(8, 1, Bb), blk256, 0, stream>>>(
        Xt, G2, e, Nn, Cc, Cc, Cc, (long long)Nn * Cc, 0, (long long)Nn * Cc, 1.f);
    gemm_sim_exp<<<dim3(8, 1, Bb), blk256, 0, stream>>>(e, T, E, rsp);
    gemm_u_scaled<<<dim3(16, 1, Bb), blk256, 0, stream>>>(E, T, u, rsp);
    gemm_ctx_ln1<<<dim3(1, 8, Bb), blk256, 0, stream>>>(
        WvB, u, X, Z1, pp1, Cc, (long long)Nn * Cc);
    ln1_norm_transpose<<<dim3(Nn / 64, Cc / 64, Bb), blk256, 0, stream>>>(
        Z1, pp1, gamma, beta, XoutT);
    gemm_tn<bf16, true, 1, 0><<<dim3(8, 1, Bb), blk256, 0, stream>>>(
        XoutT, Wf1B, hT, Nn, Cc, Cc, Cc, (long long)Nn * Cc, 0, (long long)Nn * Cc, 1.f);
    gemm_ffn_ln2<<<dim3(8, 1, Bb), blk256, 0, stream>>>(
        hT, Wf2B, Z1, pp1, gamma, beta, Z2, pp2, Cc, (long long)Nn * Cc);
    ln2_final<<<dim3(64, Bb), blk256, 0, stream>>>(Z2, pp2, gamma, beta, out);
}